// Round 2
// baseline (2408.262 us; speedup 1.0000x reference)
//
#include <hip/hip_runtime.h>
#include <cstddef>

// Problem constants
#define BB 32
#define NN 128
#define PP 8128
#define NCHUNK 4096      // 32 b * 128 j
#define QGRID 1280       // persistent blocks (256 CU * 5)

typedef __attribute__((ext_vector_type(8))) short short8;
typedef __attribute__((ext_vector_type(4))) float floatx4;

union U4S8 { uint4 u; short8 s; };
__device__ __forceinline__ short8 as_s8(uint4 v){ U4S8 x; x.u = v; return x.s; }

// ---------- bf16 helpers ----------
__device__ __forceinline__ unsigned pack_bf16(float a, float b){
  union{float f;unsigned u;}xa,xb; xa.f=a; xb.f=b;
  unsigned ua=xa.u, ub=xb.u;
  ua = (ua + 0x7fffu + ((ua>>16)&1u)) >> 16;
  ub = (ub + 0x7fffu + ((ub>>16)&1u)) >> 16;
  return (ua & 0xffffu) | (ub << 16);
}
__device__ __forceinline__ unsigned short bf16_1(float a){
  union{float f;unsigned u;}x; x.f=a;
  return (unsigned short)((x.u + 0x7fffu + ((x.u>>16)&1u)) >> 16);
}
__device__ __forceinline__ float sigf(float x){ return 1.f/(1.f + __expf(-x)); }

// ---------- weight conversion + round-0 tables + queue-counter init ----------
__global__ __launch_bounds__(256,4) void conv_w_kernel(
  const float* __restrict__ Wl_e, const float* __restrict__ Wm_e,
  const float* __restrict__ Wu_e, const float* __restrict__ Wu_m,
  const float* __restrict__ Wr1, const float* __restrict__ Wr2,
  const float* __restrict__ emb,
  unsigned* __restrict__ wT, unsigned* __restrict__ wr1T,
  unsigned* __restrict__ wr2T,
  float* __restrict__ embZ, float* __restrict__ embM, float* __restrict__ embU,
  unsigned* __restrict__ qctr)
{
  int tid = blockIdx.x*256 + threadIdx.x;   // 65536 total
  if (tid < 16) qctr[tid] = QGRID;          // reset per-round task counters每 launch
  if (tid < 2048) {   // Wr2 [256][10] -> B-frag layout [16 cols][128 k2], zero-padded
    int c = tid >> 7, k2 = tid & 127;
    unsigned v = 0;
    if (c < 10) v = pack_bf16(Wr2[(2*k2)*10 + c], Wr2[(2*k2+1)*10 + c]);
    wr2T[c*128 + k2] = v;
  }
  if (tid >= 4096 && tid < 5632) {   // round-0 tables: emb(4x128) @ W(128x128), f32
    int idx = tid - 4096;            // 0..1535
    int tb = idx >> 9;               // 0..2
    int r  = idx & 511;
    int id = r >> 7, c = r & 127;
    const float* W = (tb==0) ? Wl_e : (tb==1) ? Wm_e : Wu_e;
    float s = 0.f;
    #pragma unroll 4
    for (int k = 0; k < 128; ++k) s += emb[id*128 + k] * W[(size_t)k*128 + c];
    float* T = (tb==0) ? embZ : (tb==1) ? embM : embU;
    T[r] = s;
  }
  if (tid < 32768) {
    int mat = tid >> 13, r = tid & 8191;
    int k2 = r >> 7, c = r & 127;
    const float* W = (mat==0) ? Wl_e : (mat==1) ? Wm_e : (mat==2) ? Wu_e : Wu_m;
    wT[mat*8192 + c*64 + k2] = pack_bf16(W[(2*k2)*128 + c], W[(2*k2+1)*128 + c]);
  } else {
    int r = tid - 32768;
    int k2 = r >> 8, c = r & 255;
    wr1T[(size_t)c*128 + k2] = pack_bf16(Wr1[(2*k2)*256 + c], Wr1[(2*k2+1)*256 + c]);
  }
}

// ---------- fused GRU + node projections ----------
__global__ __launch_bounds__(256,4) void gru_proj_kernel(
  int do_gru,
  const float* __restrict__ ms, const float* __restrict__ h_in, float* __restrict__ h_out,
  const float* __restrict__ W_ih, const float* __restrict__ W_hh,
  const float* __restrict__ b_ih, const float* __restrict__ b_hh,
  const float* __restrict__ Wl_w, const float* __restrict__ Wl_v,
  const float* __restrict__ Wm_w, const float* __restrict__ Wm_v,
  const int* __restrict__ event_nums,
  float* __restrict__ a_l, float* __restrict__ b_l,
  float* __restrict__ a_m, float* __restrict__ b_m)
{
  __shared__ float h_s[4][128];
  __shared__ float ms_s[4][128];
  const int t = threadIdx.x, blk = blockIdx.x;
  const int b = blk >> 5, n0 = (blk & 31) * 4;
  const int vn = event_nums[b];
  const int g = t >> 6, l = t & 63;
  const int row = b*128 + n0 + g;

  h_s[g][l]    = h_in[(size_t)row*128 + l];
  h_s[g][l+64] = h_in[(size_t)row*128 + l + 64];
  if (do_gru) {
    ms_s[g][l]    = ms[(size_t)row*128 + l];
    ms_s[g][l+64] = ms[(size_t)row*128 + l + 64];
  }
  __syncthreads();

  if (do_gru) {
    float acc[12] = {};
    #pragma unroll 4
    for (int k = 0; k < 128; ++k) {
      float mv = ms_s[g][k], hv = h_s[g][k];
      #pragma unroll
      for (int u = 0; u < 6; ++u) {
        acc[u]   += mv * W_ih[(size_t)k*384 + l + 64*u];
        acc[6+u] += hv * W_hh[(size_t)k*384 + l + 64*u];
      }
    }
    const bool valid = (n0 + g) < vn;
    float hnew[2];
    #pragma unroll
    for (int u = 0; u < 2; ++u) {
      int c = l + 64*u;
      float ir = acc[u]     + b_ih[c];
      float iz = acc[u+2]   + b_ih[128+c];
      float in_= acc[u+4]   + b_ih[256+c];
      float hr = acc[6+u]   + b_hh[c];
      float hz = acc[8+u]   + b_hh[128+c];
      float hn = acc[10+u]  + b_hh[256+c];
      float r  = sigf(ir + hr);
      float zg = sigf(iz + hz);
      float nn = tanhf(in_ + r*hn);
      float hold = h_s[g][c];
      hnew[u] = valid ? (1.f - zg)*nn + zg*hold : hold;
    }
    __syncthreads();
    #pragma unroll
    for (int u = 0; u < 2; ++u) {
      int c = l + 64*u;
      h_s[g][c] = hnew[u];
      h_out[(size_t)row*128 + c] = hnew[u];
    }
    __syncthreads();
  }

  {
    const float* Wp[4] = {Wl_w, Wl_v, Wm_w, Wm_v};
    float* Op[4] = {a_l, b_l, a_m, b_m};
    float acc2[8] = {};
    #pragma unroll 4
    for (int k = 0; k < 128; ++k) {
      float hv = h_s[g][k];
      #pragma unroll
      for (int u = 0; u < 8; ++u)
        acc2[u] += hv * Wp[u>>1][(size_t)k*128 + l + 64*(u&1)];
    }
    #pragma unroll
    for (int u = 0; u < 8; ++u)
      Op[u>>1][(size_t)row*128 + l + 64*(u&1)] = acc2[u];
  }
}

// MFMA quarter-pass helpers (A from registers / from LDS m_a)
#define MFMA_HALF_REG(WPTR, ACC, KB0)                                            \
  {                                                                              \
    uint4 bb[2][4];                                                              \
    _Pragma("unroll")                                                            \
    for (int k2 = 0; k2 < 2; ++k2)                                               \
      _Pragma("unroll")                                                          \
      for (int ct = 0; ct < 4; ++ct)                                             \
        bb[k2][ct] = *(const uint4*)((WPTR) + colg[ct]*64 + ((KB0)+k2)*16 + q*4);\
    _Pragma("unroll")                                                            \
    for (int k2 = 0; k2 < 2; ++k2)                                               \
      _Pragma("unroll")                                                          \
      for (int rt = 0; rt < 2; ++rt)                                             \
        if (rt < nvt) {                                                          \
          _Pragma("unroll")                                                      \
          for (int ct = 0; ct < 4; ++ct)                                         \
            ACC[rt][ct] = __builtin_amdgcn_mfma_f32_16x16x32_bf16(               \
              as_s8(eA[rt][(KB0)+k2]), as_s8(bb[k2][ct]), ACC[rt][ct], 0,0,0);   \
        }                                                                        \
  }

#define MFMA_HALF_LDS(WPTR, ACC, KB0)                                            \
  {                                                                              \
    uint4 bb[2][4];                                                              \
    _Pragma("unroll")                                                            \
    for (int k2 = 0; k2 < 2; ++k2)                                               \
      _Pragma("unroll")                                                          \
      for (int ct = 0; ct < 4; ++ct)                                             \
        bb[k2][ct] = *(const uint4*)((WPTR) + colg[ct]*64 + ((KB0)+k2)*16 + q*4);\
    _Pragma("unroll")                                                            \
    for (int k2 = 0; k2 < 2; ++k2)                                               \
      _Pragma("unroll")                                                          \
      for (int rt = 0; rt < 2; ++rt)                                             \
        if (rt < nvt) {                                                          \
          uint4 a = *(const uint4*)&m_a[arowi[rt]*68 + ((KB0)+k2)*16 + q*4];     \
          _Pragma("unroll")                                                      \
          for (int ct = 0; ct < 4; ++ct)                                         \
            ACC[rt][ct] = __builtin_amdgcn_mfma_f32_16x16x32_bf16(               \
              as_s8(a), as_s8(bb[k2][ct]), ACC[rt][ct], 0,0,0);                  \
        }                                                                        \
  }

// ---------- edge round 0: table-driven, persistent blocks, dynamic queue ----------
__global__ __launch_bounds__(256,5) void edge_round_first(
  unsigned* __restrict__ eg,
  const unsigned* __restrict__ wT,
  const int* __restrict__ ids,
  const float* __restrict__ embZ, const float* __restrict__ embM,
  const float* __restrict__ embU,
  const float* __restrict__ a_l, const float* __restrict__ b_l,
  const float* __restrict__ a_m, const float* __restrict__ b_m,
  const float* __restrict__ bl1, const float* __restrict__ wl2,
  const float* __restrict__ bl2, const float* __restrict__ bm,
  const float* __restrict__ bu,
  const int* __restrict__ event_nums,
  float* __restrict__ ms, unsigned* __restrict__ qc)
{
  __shared__ unsigned m_a[64*68];
  __shared__ float adj[64], msum[128];
  __shared__ float tabZ[512], tabM[512], tabU[512];
  __shared__ int id_s[64];
  __shared__ int task_s;
  unsigned short* m16 = (unsigned short*)m_a;

  const int t = threadIdx.x;
  const int lane = t & 63, wv = t >> 6;
  const int q = lane >> 4, n = lane & 15;
  const int rh2 = wv >> 1, ch = wv & 1;
  int colg[4];
  #pragma unroll
  for (int ct = 0; ct < 4; ++ct) colg[ct] = ch*64 + ct*16 + n;
  int arowi[2];
  #pragma unroll
  for (int rt = 0; rt < 2; ++rt) arowi[rt] = rh2*32 + rt*16 + n;
  const unsigned* wum = wT + 24576;
  const float bl2v = bl2[0];

  for (int i = t; i < 512; i += 256) {
    tabZ[i] = embZ[i]; tabM[i] = embM[i]; tabU[i] = embU[i];
  }
  __syncthreads();

  int chunk = blockIdx.x;
  while (chunk < NCHUNK) {
    const int b = chunk >> 7, j = chunk & 127;
    const int vn = event_nums[b];
    if (j < vn) {
      unsigned* eblk = eg + (size_t)(b*128 + j) * 8192;
      float bLv[4], bMv[4];
      #pragma unroll
      for (int ct = 0; ct < 4; ++ct) {
        int c = colg[ct];
        bLv[ct] = b_l[(size_t)(b*128 + j)*128 + c] + bl1[c];
        bMv[ct] = b_m[(size_t)(b*128 + j)*128 + c] + bm[c];
      }
      if (t < 128) msum[t] = 0.f;
      const int nhalf = (vn > 64) ? 2 : 1;
      for (int hh = 0; hh < nhalf; ++hh) {
        const int row0 = hh*64;
        int vnl = vn - row0; if (vnl > 64) vnl = 64;
        int nvt = (vnl - rh2*32 + 15) >> 4;
        nvt = nvt < 0 ? 0 : (nvt > 2 ? 2 : nvt);

        if (t < 64) {
          adj[t] = 0.f;
          id_s[t] = ids[((size_t)(b*128 + row0 + t))*128 + j];
        }
        const float* aLb = a_l + (size_t)(b*128 + row0)*128;
        const float* aMb = a_m + (size_t)(b*128 + row0)*128;
        float alv[2][4][4];
        #pragma unroll
        for (int rt = 0; rt < 2; ++rt)
          if (rt < nvt) {
            #pragma unroll
            for (int ct = 0; ct < 4; ++ct)
              #pragma unroll
              for (int r = 0; r < 4; ++r)
                alv[rt][ct][r] = aLb[(size_t)(rh2*32 + rt*16 + q*4 + r)*128 + colg[ct]];
          }
        __syncthreads();   // B1: id_s/adj (and msum at first half) ready

        // Z epilogue from tables
        {
          float wl2v[4];
          #pragma unroll
          for (int ct = 0; ct < 4; ++ct) wl2v[ct] = wl2[colg[ct]];
          #pragma unroll
          for (int rt = 0; rt < 2; ++rt) {
            if (rt < nvt) {
              float szr[4] = {0.f,0.f,0.f,0.f};
              #pragma unroll
              for (int ct = 0; ct < 4; ++ct) {
                #pragma unroll
                for (int r = 0; r < 4; ++r) {
                  int lrow = rh2*32 + rt*16 + q*4 + r;
                  float zv = fmaxf(tabZ[id_s[lrow]*128 + colg[ct]] + alv[rt][ct][r] + bLv[ct], 0.f);
                  szr[r] += zv * wl2v[ct];
                }
              }
              #pragma unroll
              for (int r = 0; r < 4; ++r) {
                szr[r] += __shfl_xor(szr[r], 1);
                szr[r] += __shfl_xor(szr[r], 2);
                szr[r] += __shfl_xor(szr[r], 4);
                szr[r] += __shfl_xor(szr[r], 8);
              }
              if (n == 0) {
                #pragma unroll
                for (int r = 0; r < 4; ++r)
                  atomicAdd(&adj[rh2*32 + rt*16 + q*4 + r], szr[r]);
              }
            }
          }
        }
        float amv[2][4][4];
        #pragma unroll
        for (int rt = 0; rt < 2; ++rt)
          if (rt < nvt) {
            #pragma unroll
            for (int ct = 0; ct < 4; ++ct)
              #pragma unroll
              for (int r = 0; r < 4; ++r)
                amv[rt][ct][r] = aMb[(size_t)(rh2*32 + rt*16 + q*4 + r)*128 + colg[ct]];
          }
        __syncthreads();   // B2: adj final

        // M epilogue from tables -> m16, msum (per-thread sigmoid, no svec)
        {
          float colsum[4] = {0.f,0.f,0.f,0.f};
          #pragma unroll
          for (int rt = 0; rt < 2; ++rt) {
            if (rt < nvt) {
              #pragma unroll
              for (int r = 0; r < 4; ++r) {
                int lrow = rh2*32 + rt*16 + q*4 + r;
                float sc = (lrow < vnl) ? sigf(adj[lrow] + bl2v) : 0.f;
                #pragma unroll
                for (int ct = 0; ct < 4; ++ct) {
                  float mv = fmaxf(tabM[id_s[lrow]*128 + colg[ct]] + amv[rt][ct][r] + bMv[ct], 0.f) * sc;
                  m16[lrow*136 + colg[ct]] = bf16_1(mv);
                  colsum[ct] += mv;
                }
              }
            }
          }
          #pragma unroll
          for (int ct = 0; ct < 4; ++ct) {
            float v = colsum[ct];
            v += __shfl_xor(v, 16);
            v += __shfl_xor(v, 32);
            if (lane < 16) atomicAdd(&msum[colg[ct]], v);
          }
        }
        __syncthreads();   // B3: m16/msum final

        // U = tabU gather + M@Wu_m
        floatx4 au[2][4];
        #pragma unroll
        for (int rt = 0; rt < 2; ++rt)
          #pragma unroll
          for (int ct = 0; ct < 4; ++ct) {
            au[rt][ct] = (floatx4){0.f,0.f,0.f,0.f};
            if (rt < nvt) {
              #pragma unroll
              for (int r = 0; r < 4; ++r) {
                int lrow = rh2*32 + rt*16 + q*4 + r;
                au[rt][ct][r] = tabU[id_s[lrow]*128 + colg[ct]];
              }
            }
          }
        MFMA_HALF_LDS(wum, au, 0)
        MFMA_HALF_LDS(wum, au, 2)
        __syncthreads();   // B4: done reading m_a

        {
          #pragma unroll
          for (int rt = 0; rt < 2; ++rt)
            if (rt < nvt) {
              #pragma unroll
              for (int ct = 0; ct < 4; ++ct) {
                float buv = bu[colg[ct]];
                #pragma unroll
                for (int r = 0; r < 4; ++r) {
                  int lrow = rh2*32 + rt*16 + q*4 + r;
                  m16[lrow*136 + colg[ct]] = bf16_1(fmaxf(au[rt][ct][r] + buv, 0.f));
                }
              }
            }
        }
        __syncthreads();   // B5: m16 final
        #pragma unroll
        for (int it = 0; it < 4; ++it) {
          int f = it*256 + t;
          int lr = f >> 4, c4 = (f & 15) * 4;
          if (row0 + lr < vn)
            *(uint4*)&eblk[(size_t)(row0 + lr)*64 + c4] = *(const uint4*)&m_a[lr*68 + c4];
        }
      }
      if (t < 128) ms[(size_t)(b*128 + j)*128 + t] = msum[t];   // exclusive owner: plain store
    }
    if (t == 0) task_s = (int)atomicAdd(qc, 1u);
    __syncthreads();
    chunk = task_s;
    __syncthreads();
  }
}

// ---------- edge rounds >=1: persistent blocks, E-tile in registers ----------
__global__ __launch_bounds__(256,5) void edge_round_rest(
  unsigned* __restrict__ eg,
  const unsigned* __restrict__ wT,
  const float* __restrict__ a_l, const float* __restrict__ b_l,
  const float* __restrict__ a_m, const float* __restrict__ b_m,
  const float* __restrict__ bl1, const float* __restrict__ wl2,
  const float* __restrict__ bl2, const float* __restrict__ bm,
  const float* __restrict__ bu,
  const int* __restrict__ event_nums,
  float* __restrict__ ms, unsigned* __restrict__ qc)
{
  __shared__ unsigned m_a[64*68];
  __shared__ float adj[64], msum[128];
  __shared__ int task_s;
  unsigned short* m16 = (unsigned short*)m_a;

  const int t = threadIdx.x;
  const int lane = t & 63, wv = t >> 6;
  const int q = lane >> 4, n = lane & 15;
  const int rh2 = wv >> 1, ch = wv & 1;
  int colg[4];
  #pragma unroll
  for (int ct = 0; ct < 4; ++ct) colg[ct] = ch*64 + ct*16 + n;
  int arowi[2];
  #pragma unroll
  for (int rt = 0; rt < 2; ++rt) arowi[rt] = rh2*32 + rt*16 + n;

  const unsigned* wz  = wT;
  const unsigned* wm  = wT + 8192;
  const unsigned* wue = wT + 16384;
  const unsigned* wum = wT + 24576;
  const float bl2v = bl2[0];

  int chunk = blockIdx.x;
  while (chunk < NCHUNK) {
    const int b = chunk >> 7, j = chunk & 127;
    const int vn = event_nums[b];
    if (j < vn) {
      unsigned* eblk = eg + (size_t)(b*128 + j) * 8192;
      float bLv[4], bMv[4];
      #pragma unroll
      for (int ct = 0; ct < 4; ++ct) {
        int c = colg[ct];
        bLv[ct] = b_l[(size_t)(b*128 + j)*128 + c] + bl1[c];
        bMv[ct] = b_m[(size_t)(b*128 + j)*128 + c] + bm[c];
      }
      if (t < 128) msum[t] = 0.f;
      const int nhalf = (vn > 64) ? 2 : 1;
      for (int hh = 0; hh < nhalf; ++hh) {
        const int row0 = hh*64;
        int vnl = vn - row0; if (vnl > 64) vnl = 64;
        int nvt = (vnl - rh2*32 + 15) >> 4;
        nvt = nvt < 0 ? 0 : (nvt > 2 ? 2 : nvt);

        if (t < 64) adj[t] = 0.f;

        // E-tile fragments -> registers (rows >= vn may be garbage; masked downstream)
        uint4 eA[2][4];
        #pragma unroll
        for (int rt = 0; rt < 2; ++rt)
          if (rt < nvt) {
            #pragma unroll
            for (int kb = 0; kb < 4; ++kb)
              eA[rt][kb] = *(const uint4*)&eblk[(size_t)(row0 + arowi[rt])*64 + kb*16 + q*4];
          }
        const float* aLb = a_l + (size_t)(b*128 + row0)*128;
        const float* aMb = a_m + (size_t)(b*128 + row0)*128;

        // ---------- PASS Z (pre-barrier; from registers) ----------
        floatx4 az[2][4];
        #pragma unroll
        for (int rt = 0; rt < 2; ++rt)
          #pragma unroll
          for (int ct = 0; ct < 4; ++ct) az[rt][ct] = (floatx4){0.f,0.f,0.f,0.f};
        MFMA_HALF_REG(wz, az, 0)
        float alv[2][4][4];
        #pragma unroll
        for (int rt = 0; rt < 2; ++rt)
          if (rt < nvt) {
            #pragma unroll
            for (int ct = 0; ct < 4; ++ct)
              #pragma unroll
              for (int r = 0; r < 4; ++r)
                alv[rt][ct][r] = aLb[(size_t)(rh2*32 + rt*16 + q*4 + r)*128 + colg[ct]];
          }
        MFMA_HALF_REG(wz, az, 2)
        __syncthreads();   // B1: adj zero (and msum at first half) ready

        // Z epilogue
        {
          float wl2v[4];
          #pragma unroll
          for (int ct = 0; ct < 4; ++ct) wl2v[ct] = wl2[colg[ct]];
          #pragma unroll
          for (int rt = 0; rt < 2; ++rt) {
            if (rt < nvt) {
              float szr[4] = {0.f,0.f,0.f,0.f};
              #pragma unroll
              for (int ct = 0; ct < 4; ++ct) {
                #pragma unroll
                for (int r = 0; r < 4; ++r) {
                  float zv = fmaxf(az[rt][ct][r] + alv[rt][ct][r] + bLv[ct], 0.f);
                  szr[r] += zv * wl2v[ct];
                }
              }
              #pragma unroll
              for (int r = 0; r < 4; ++r) {
                szr[r] += __shfl_xor(szr[r], 1);
                szr[r] += __shfl_xor(szr[r], 2);
                szr[r] += __shfl_xor(szr[r], 4);
                szr[r] += __shfl_xor(szr[r], 8);
              }
              if (n == 0) {
                #pragma unroll
                for (int r = 0; r < 4; ++r)
                  atomicAdd(&adj[rh2*32 + rt*16 + q*4 + r], szr[r]);
              }
            }
          }
        }

        // ---------- PASS M (MFMA before barrier; epilogue needs adj) ----------
        floatx4 am[2][4];
        #pragma unroll
        for (int rt = 0; rt < 2; ++rt)
          #pragma unroll
          for (int ct = 0; ct < 4; ++ct) am[rt][ct] = (floatx4){0.f,0.f,0.f,0.f};
        MFMA_HALF_REG(wm, am, 0)
        float amv[2][4][4];
        #pragma unroll
        for (int rt = 0; rt < 2; ++rt)
          if (rt < nvt) {
            #pragma unroll
            for (int ct = 0; ct < 4; ++ct)
              #pragma unroll
              for (int r = 0; r < 4; ++r)
                amv[rt][ct][r] = aMb[(size_t)(rh2*32 + rt*16 + q*4 + r)*128 + colg[ct]];
          }
        MFMA_HALF_REG(wm, am, 2)
        __syncthreads();   // B2: adj final

        // M epilogue (per-thread sigmoid, no svec array)
        {
          float colsum[4] = {0.f,0.f,0.f,0.f};
          #pragma unroll
          for (int rt = 0; rt < 2; ++rt) {
            if (rt < nvt) {
              #pragma unroll
              for (int r = 0; r < 4; ++r) {
                int lrow = rh2*32 + rt*16 + q*4 + r;
                float sc = (lrow < vnl) ? sigf(adj[lrow] + bl2v) : 0.f;
                #pragma unroll
                for (int ct = 0; ct < 4; ++ct) {
                  float mv = fmaxf(am[rt][ct][r] + amv[rt][ct][r] + bMv[ct], 0.f) * sc;
                  m16[lrow*136 + colg[ct]] = bf16_1(mv);
                  colsum[ct] += mv;
                }
              }
            }
          }
          #pragma unroll
          for (int ct = 0; ct < 4; ++ct) {
            float v = colsum[ct];
            v += __shfl_xor(v, 16);
            v += __shfl_xor(v, 32);
            if (lane < 16) atomicAdd(&msum[colg[ct]], v);
          }
        }
        __syncthreads();   // B3: m16/msum final

        // ---------- PASS U ----------
        floatx4 au[2][4];
        #pragma unroll
        for (int rt = 0; rt < 2; ++rt)
          #pragma unroll
          for (int ct = 0; ct < 4; ++ct) au[rt][ct] = (floatx4){0.f,0.f,0.f,0.f};
        MFMA_HALF_REG(wue, au, 0)
        MFMA_HALF_REG(wue, au, 2)
        MFMA_HALF_LDS(wum, au, 0)
        MFMA_HALF_LDS(wum, au, 2)
        __syncthreads();   // B4: done reading m_a

        {
          #pragma unroll
          for (int rt = 0; rt < 2; ++rt)
            if (rt < nvt) {
              #pragma unroll
              for (int ct = 0; ct < 4; ++ct) {
                float buv = bu[colg[ct]];
                #pragma unroll
                for (int r = 0; r < 4; ++r) {
                  int lrow = rh2*32 + rt*16 + q*4 + r;
                  m16[lrow*136 + colg[ct]] = bf16_1(fmaxf(au[rt][ct][r] + buv, 0.f));
                }
              }
            }
        }
        __syncthreads();   // B5: m16 final
        #pragma unroll
        for (int it = 0; it < 4; ++it) {
          int f = it*256 + t;
          int lr = f >> 4, c4 = (f & 15) * 4;
          if (row0 + lr < vn)
            *(uint4*)&eblk[(size_t)(row0 + lr)*64 + c4] = *(const uint4*)&m_a[lr*68 + c4];
        }
      }
      if (t < 128) ms[(size_t)(b*128 + j)*128 + t] = msum[t];   // exclusive owner: plain store
    }
    if (t == 0) task_s = (int)atomicAdd(qc, 1u);
    __syncthreads();
    chunk = task_s;
    __syncthreads();
  }
}

// ---------- MFMA readout, both GEMMs on matrix cores ----------
__global__ __launch_bounds__(256,4) void readout_mfma(
  const unsigned* __restrict__ eg,
  const unsigned* __restrict__ wr1T,
  const unsigned* __restrict__ wr2T,
  const float* __restrict__ br1, const float* __restrict__ br2,
  const int* __restrict__ event_nums, float* __restrict__ out)
{
  __shared__ unsigned f_s[64*132];
  __shared__ int iu_s[64], ju_s[64];
  unsigned short* h16 = (unsigned short*)f_s;

  const int t = threadIdx.x;
  const int b = blockIdx.x / 127, pb = blockIdx.x % 127;
  const int vn = event_nums[b];

  if (t < 64) {
    int p = pb*64 + t;
    float disc = (float)((2*NN-1)*(2*NN-1) - 8*p);
    int iu = (int)(((float)(2*NN-1) - sqrtf(disc)) * 0.5f);
    if (iu < 0) iu = 0; if (iu > NN-2) iu = NN-2;
    while (iu < NN-2 && ((iu+1)*(2*NN-2-iu))/2 <= p) ++iu;
    while (iu > 0 && (iu*(2*NN-1-iu))/2 > p) --iu;
    int ju = p - (iu*(2*NN-1-iu))/2 + iu + 1;
    iu_s[t] = iu; ju_s[t] = ju;
  }
  __syncthreads();

  #pragma unroll
  for (int it = 0; it < 8; ++it) {
    int f4 = it*1024 + t*4;
    int pr = f4 >> 7, w = f4 & 127;
    int side = w >> 6, k2 = w & 63;
    int iu = iu_s[pr], ju = ju_s[pr];
    size_t base = side ? (((size_t)(b*128 + iu))*128 + ju)*64
                       : (((size_t)(b*128 + ju))*128 + iu)*64;
    *(uint4*)&f_s[pr*132 + w] = *(const uint4*)&eg[base + k2];
  }
  __syncthreads();

  const int lane = t & 63, wv = t >> 6;
  const int q = lane >> 4, n = lane & 15;
  int colg[4];
  #pragma unroll
  for (int ct = 0; ct < 4; ++ct) colg[ct] = wv*64 + ct*16 + n;

  floatx4 acc[4][4];
  #pragma unroll
  for (int rt = 0; rt < 4; ++rt)
    #pragma unroll
    for (int ct = 0; ct < 4; ++ct) acc[rt][ct] = (floatx4){0.f,0.f,0.f,0.f};

  #pragma unroll
  for (int kb = 0; kb < 8; ++kb) {
    uint4 bb[4];
    #pragma unroll
    for (int ct = 0; ct < 4; ++ct) bb[ct] = *(const uint4*)(wr1T + (size_t)colg[ct]*128 + kb*16 + q*4);
    #pragma unroll
    for (int rt = 0; rt < 4; ++rt) {
      uint4 a = *(const uint4*)&f_s[(rt*16 + n)*132 + kb*16 + q*4];
      #pragma unroll
      for (int ct = 0; ct < 4; ++ct)
        acc[rt][ct] = __builtin_amdgcn_mfma_f32_16x16x32_bf16(as_s8(a), as_s8(bb[ct]), acc[rt][ct], 0, 0, 0);
    }
  }
  __syncthreads();

  {
    float brv[4];
    #pragma unroll
    for (int ct = 0; ct < 4; ++ct) brv[ct] = br1[colg[ct]];
    #pragma unroll
    for (int rt = 0; rt < 4; ++rt)
      #pragma unroll
      for (int ct = 0; ct < 4; ++ct)
        #pragma unroll
        for (int r = 0; r < 4; ++r) {
          int pr = rt*16 + q*4 + r;
          h16[pr*264 + colg[ct]] = bf16_1(fmaxf(acc[rt][ct][r] + brv[ct], 0.f));
        }
  }
  __syncthreads();

  floatx4 acc2 = (floatx4){0.f,0.f,0.f,0.f};
  #pragma unroll
  for (int kb = 0; kb < 8; ++kb) {
    uint4 bb = *(const uint4*)(wr2T + n*128 + kb*16 + q*4);
    uint4 a  = *(const uint4*)&f_s[(wv*16 + n)*132 + kb*16 + q*4];
    acc2 = __builtin_amdgcn_mfma_f32_16x16x32_bf16(as_s8(a), as_s8(bb), acc2, 0, 0, 0);
  }

  if (n < 10) {
    float bias = br2[n];
    #pragma unroll
    for (int r = 0; r < 4; ++r) {
      int pr = wv*16 + q*4 + r;
      int iu = iu_s[pr], ju = ju_s[pr];
      if (ju < vn) {
        int idx = iu*vn - (iu*(iu+1))/2 + (ju - iu - 1);
        out[(((size_t)b*5 + (n>>1))*PP + idx)*2 + (n&1)] = acc2[r] + bias;
      }
    }
  }
}

extern "C" void kernel_launch(void* const* d_in, const int* in_sizes, int n_in,
                              void* d_out, int out_size, void* d_ws, size_t ws_size,
                              hipStream_t stream) {
  const int*   edge_ids      = (const int*)d_in[0];
  const float* node_features = (const float*)d_in[1];
  const int*   event_nums    = (const int*)d_in[3];
  const float* emb  = (const float*)d_in[4];
  const float* Wl_e = (const float*)d_in[5];
  const float* Wl_w = (const float*)d_in[6];
  const float* Wl_v = (const float*)d_in[7];
  const float* bl1  = (const float*)d_in[8];
  const float* wl2  = (const float*)d_in[9];
  const float* bl2  = (const float*)d_in[10];
  const float* Wm_w = (const float*)d_in[11];
  const float* Wm_v = (const float*)d_in[12];
  const float* Wm_e = (const float*)d_in[13];
  const float* bm   = (const float*)d_in[14];
  const float* Wu_e = (const float*)d_in[15];
  const float* Wu_m = (const float*)d_in[16];
  const float* bu   = (const float*)d_in[17];
  const float* W_ih = (const float*)d_in[18];
  const float* W_hh = (const float*)d_in[19];
  const float* b_ih = (const float*)d_in[20];
  const float* b_hh = (const float*)d_in[21];
  const float* Wr1  = (const float*)d_in[22];
  const float* br1  = (const float*)d_in[23];
  const float* Wr2  = (const float*)d_in[24];
  const float* br2  = (const float*)d_in[25];

  const size_t SZ_E = (size_t)134217728;       // B*N*N*64 u32
  const size_t SZ_S = (size_t)2097152;         // B*N*128 f32
  const size_t SZ_W = (size_t)131072;          // 32768 u32
  const size_t SZ_W2 = (size_t)8192;           // 2048 u32
  const size_t SZ_TAB = (size_t)2048;          // 512 f32 each
  const size_t SZ_Q = (size_t)64;              // 16 u32 task counters
  const size_t need = SZ_E + 6*SZ_S + 2*SZ_W + SZ_W2 + 3*SZ_TAB + SZ_Q;

  hipMemsetAsync(d_out, 0, (size_t)out_size * sizeof(float), stream);
  if (ws_size < need) return;

  char* w = (char*)d_ws;
  unsigned* eg   = (unsigned*)w; w += SZ_E;
  float* h_ws = (float*)w; w += SZ_S;
  float* a_l  = (float*)w; w += SZ_S;
  float* b_l  = (float*)w; w += SZ_S;
  float* a_m  = (float*)w; w += SZ_S;
  float* b_m  = (float*)w; w += SZ_S;
  float* ms   = (float*)w; w += SZ_S;
  unsigned* wT   = (unsigned*)w; w += SZ_W;
  unsigned* wr1T = (unsigned*)w; w += SZ_W;
  unsigned* wr2T = (unsigned*)w; w += SZ_W2;
  float* embZ = (float*)w; w += SZ_TAB;
  float* embM = (float*)w; w += SZ_TAB;
  float* embU = (float*)w; w += SZ_TAB;
  unsigned* qctr = (unsigned*)w; w += SZ_Q;

  hipLaunchKernelGGL(conv_w_kernel, dim3(256), dim3(256), 0, stream,
      Wl_e, Wm_e, Wu_e, Wu_m, Wr1, Wr2, emb, wT, wr1T, wr2T, embZ, embM, embU, qctr);

  hipLaunchKernelGGL(gru_proj_kernel, dim3(1024), dim3(256), 0, stream,
      0, ms, node_features, h_ws, W_ih, W_hh, b_ih, b_hh,
      Wl_w, Wl_v, Wm_w, Wm_v, event_nums, a_l, b_l, a_m, b_m);

  for (int r = 0; r < 3; ++r) {
    if (r == 0) {
      hipLaunchKernelGGL(edge_round_first, dim3(QGRID), dim3(256), 0, stream,
          eg, wT, edge_ids, embZ, embM, embU,
          a_l, b_l, a_m, b_m, bl1, wl2, bl2, bm, bu, event_nums, ms, qctr + 0);
    } else {
      hipLaunchKernelGGL(edge_round_rest, dim3(QGRID), dim3(256), 0, stream,
          eg, wT, a_l, b_l, a_m, b_m, bl1, wl2, bl2, bm, bu, event_nums, ms, qctr + r);
    }
    if (r < 2) {
      const float* hin = (r == 0) ? node_features : h_ws;
      hipLaunchKernelGGL(gru_proj_kernel, dim3(1024), dim3(256), 0, stream,
          1, ms, hin, h_ws, W_ih, W_hh, b_ih, b_hh,
          Wl_w, Wl_v, Wm_w, Wm_v, event_nums, a_l, b_l, a_m, b_m);
    }
  }

  hipLaunchKernelGGL(readout_mfma, dim3(BB*127), dim3(256), 0, stream,
      eg, wr1T, wr2T, br1, br2, event_nums, (float*)d_out);
}

// Round 3
// 2066.540 us; speedup vs baseline: 1.1654x; 1.1654x over previous
//
#include <hip/hip_runtime.h>
#include <cstddef>

// Problem constants
#define BB 32
#define NN 128
#define PP 8128
#define NCHUNK 4096      // 32 b * 128 j
#define QGRID 1024       // persistent blocks (256 CU * 4 resident)

typedef __attribute__((ext_vector_type(8))) short short8;
typedef __attribute__((ext_vector_type(4))) float floatx4;

union U4S8 { uint4 u; short8 s; };
__device__ __forceinline__ short8 as_s8(uint4 v){ U4S8 x; x.u = v; return x.s; }

// ---------- bf16 helpers ----------
__device__ __forceinline__ unsigned pack_bf16(float a, float b){
  union{float f;unsigned u;}xa,xb; xa.f=a; xb.f=b;
  unsigned ua=xa.u, ub=xb.u;
  ua = (ua + 0x7fffu + ((ua>>16)&1u)) >> 16;
  ub = (ub + 0x7fffu + ((ub>>16)&1u)) >> 16;
  return (ua & 0xffffu) | (ub << 16);
}
__device__ __forceinline__ unsigned short bf16_1(float a){
  union{float f;unsigned u;}x; x.f=a;
  return (unsigned short)((x.u + 0x7fffu + ((x.u>>16)&1u)) >> 16);
}
__device__ __forceinline__ float sigf(float x){ return 1.f/(1.f + __expf(-x)); }

// ---------- weight conversion + round-0 tables + queue-counter init ----------
__global__ __launch_bounds__(256,4) void conv_w_kernel(
  const float* __restrict__ Wl_e, const float* __restrict__ Wm_e,
  const float* __restrict__ Wu_e, const float* __restrict__ Wu_m,
  const float* __restrict__ Wr1, const float* __restrict__ Wr2,
  const float* __restrict__ emb,
  unsigned* __restrict__ wT, unsigned* __restrict__ wr1T,
  unsigned* __restrict__ wr2T,
  float* __restrict__ embZ, float* __restrict__ embM, float* __restrict__ embU,
  unsigned* __restrict__ qctr)
{
  int tid = blockIdx.x*256 + threadIdx.x;   // 65536 total
  if (tid < 16) qctr[tid] = QGRID;          // reset per-round task counters each launch
  if (tid < 2048) {   // Wr2 [256][10] -> B-frag layout [16 cols][128 k2], zero-padded
    int c = tid >> 7, k2 = tid & 127;
    unsigned v = 0;
    if (c < 10) v = pack_bf16(Wr2[(2*k2)*10 + c], Wr2[(2*k2+1)*10 + c]);
    wr2T[c*128 + k2] = v;
  }
  if (tid >= 4096 && tid < 5632) {   // round-0 tables: emb(4x128) @ W(128x128), f32
    int idx = tid - 4096;            // 0..1535
    int tb = idx >> 9;               // 0..2
    int r  = idx & 511;
    int id = r >> 7, c = r & 127;
    const float* W = (tb==0) ? Wl_e : (tb==1) ? Wm_e : Wu_e;
    float s = 0.f;
    #pragma unroll 4
    for (int k = 0; k < 128; ++k) s += emb[id*128 + k] * W[(size_t)k*128 + c];
    float* T = (tb==0) ? embZ : (tb==1) ? embM : embU;
    T[r] = s;
  }
  if (tid < 32768) {
    int mat = tid >> 13, r = tid & 8191;
    int k2 = r >> 7, c = r & 127;
    const float* W = (mat==0) ? Wl_e : (mat==1) ? Wm_e : (mat==2) ? Wu_e : Wu_m;
    wT[mat*8192 + c*64 + k2] = pack_bf16(W[(2*k2)*128 + c], W[(2*k2+1)*128 + c]);
  } else {
    int r = tid - 32768;
    int k2 = r >> 8, c = r & 255;
    wr1T[(size_t)c*128 + k2] = pack_bf16(Wr1[(2*k2)*256 + c], Wr1[(2*k2+1)*256 + c]);
  }
}

// ---------- fused GRU + node projections ----------
__global__ __launch_bounds__(256,4) void gru_proj_kernel(
  int do_gru,
  const float* __restrict__ ms, const float* __restrict__ h_in, float* __restrict__ h_out,
  const float* __restrict__ W_ih, const float* __restrict__ W_hh,
  const float* __restrict__ b_ih, const float* __restrict__ b_hh,
  const float* __restrict__ Wl_w, const float* __restrict__ Wl_v,
  const float* __restrict__ Wm_w, const float* __restrict__ Wm_v,
  const int* __restrict__ event_nums,
  float* __restrict__ a_l, float* __restrict__ b_l,
  float* __restrict__ a_m, float* __restrict__ b_m)
{
  __shared__ float h_s[4][128];
  __shared__ float ms_s[4][128];
  const int t = threadIdx.x, blk = blockIdx.x;
  const int b = blk >> 5, n0 = (blk & 31) * 4;
  const int vn = event_nums[b];
  const int g = t >> 6, l = t & 63;
  const int row = b*128 + n0 + g;

  h_s[g][l]    = h_in[(size_t)row*128 + l];
  h_s[g][l+64] = h_in[(size_t)row*128 + l + 64];
  if (do_gru) {
    ms_s[g][l]    = ms[(size_t)row*128 + l];
    ms_s[g][l+64] = ms[(size_t)row*128 + l + 64];
  }
  __syncthreads();

  if (do_gru) {
    float acc[12] = {};
    #pragma unroll 4
    for (int k = 0; k < 128; ++k) {
      float mv = ms_s[g][k], hv = h_s[g][k];
      #pragma unroll
      for (int u = 0; u < 6; ++u) {
        acc[u]   += mv * W_ih[(size_t)k*384 + l + 64*u];
        acc[6+u] += hv * W_hh[(size_t)k*384 + l + 64*u];
      }
    }
    const bool valid = (n0 + g) < vn;
    float hnew[2];
    #pragma unroll
    for (int u = 0; u < 2; ++u) {
      int c = l + 64*u;
      float ir = acc[u]     + b_ih[c];
      float iz = acc[u+2]   + b_ih[128+c];
      float in_= acc[u+4]   + b_ih[256+c];
      float hr = acc[6+u]   + b_hh[c];
      float hz = acc[8+u]   + b_hh[128+c];
      float hn = acc[10+u]  + b_hh[256+c];
      float r  = sigf(ir + hr);
      float zg = sigf(iz + hz);
      float nn = tanhf(in_ + r*hn);
      float hold = h_s[g][c];
      hnew[u] = valid ? (1.f - zg)*nn + zg*hold : hold;
    }
    __syncthreads();
    #pragma unroll
    for (int u = 0; u < 2; ++u) {
      int c = l + 64*u;
      h_s[g][c] = hnew[u];
      h_out[(size_t)row*128 + c] = hnew[u];
    }
    __syncthreads();
  }

  {
    const float* Wp[4] = {Wl_w, Wl_v, Wm_w, Wm_v};
    float* Op[4] = {a_l, b_l, a_m, b_m};
    float acc2[8] = {};
    #pragma unroll 4
    for (int k = 0; k < 128; ++k) {
      float hv = h_s[g][k];
      #pragma unroll
      for (int u = 0; u < 8; ++u)
        acc2[u] += hv * Wp[u>>1][(size_t)k*128 + l + 64*(u&1)];
    }
    #pragma unroll
    for (int u = 0; u < 8; ++u)
      Op[u>>1][(size_t)row*128 + l + 64*(u&1)] = acc2[u];
  }
}

// MFMA half-pass helper: A-fragments from an LDS tile (stride 68 u32 per row)
#define MFMA_HALF(SRC, WPTR, ACC, KB0)                                           \
  {                                                                              \
    uint4 bb[2][4];                                                              \
    _Pragma("unroll")                                                            \
    for (int k2 = 0; k2 < 2; ++k2)                                               \
      _Pragma("unroll")                                                          \
      for (int ct = 0; ct < 4; ++ct)                                             \
        bb[k2][ct] = *(const uint4*)((WPTR) + colg[ct]*64 + ((KB0)+k2)*16 + q*4);\
    _Pragma("unroll")                                                            \
    for (int k2 = 0; k2 < 2; ++k2)                                               \
      _Pragma("unroll")                                                          \
      for (int rt = 0; rt < 2; ++rt)                                             \
        if (rt < nvt) {                                                          \
          uint4 a = *(const uint4*)&SRC[arowi[rt]*68 + ((KB0)+k2)*16 + q*4];     \
          _Pragma("unroll")                                                      \
          for (int ct = 0; ct < 4; ++ct)                                         \
            ACC[rt][ct] = __builtin_amdgcn_mfma_f32_16x16x32_bf16(               \
              as_s8(a), as_s8(bb[k2][ct]), ACC[rt][ct], 0,0,0);                  \
        }                                                                        \
  }

// ---------- edge round 0: table-driven, persistent blocks, dynamic queue ----------
__global__ __launch_bounds__(256,4) void edge_round_first(
  unsigned* __restrict__ eg,
  const unsigned* __restrict__ wT,
  const int* __restrict__ ids,
  const float* __restrict__ embZ, const float* __restrict__ embM,
  const float* __restrict__ embU,
  const float* __restrict__ a_l, const float* __restrict__ b_l,
  const float* __restrict__ a_m, const float* __restrict__ b_m,
  const float* __restrict__ bl1, const float* __restrict__ wl2,
  const float* __restrict__ bl2, const float* __restrict__ bm,
  const float* __restrict__ bu,
  const int* __restrict__ event_nums,
  float* __restrict__ ms, unsigned* __restrict__ qc)
{
  __shared__ unsigned m_a[64*68];
  __shared__ float adj[64], msum[128];
  __shared__ float tabZ[512], tabM[512], tabU[512];
  __shared__ int id_s[64];
  __shared__ int task_s;
  unsigned short* m16 = (unsigned short*)m_a;

  const int t = threadIdx.x;
  const int lane = t & 63, wv = t >> 6;
  const int q = lane >> 4, n = lane & 15;
  const int rh2 = wv >> 1, ch = wv & 1;
  int colg[4];
  #pragma unroll
  for (int ct = 0; ct < 4; ++ct) colg[ct] = ch*64 + ct*16 + n;
  int arowi[2];
  #pragma unroll
  for (int rt = 0; rt < 2; ++rt) arowi[rt] = rh2*32 + rt*16 + n;
  const unsigned* wum = wT + 24576;
  const float bl2v = bl2[0];
  float wl2v[4], buv[4];
  #pragma unroll
  for (int ct = 0; ct < 4; ++ct) { wl2v[ct] = wl2[colg[ct]]; buv[ct] = bu[colg[ct]]; }

  for (int i = t; i < 512; i += 256) {
    tabZ[i] = embZ[i]; tabM[i] = embM[i]; tabU[i] = embU[i];
  }
  // first use of tabs is after B1 inside the loop — that barrier publishes them

  int chunk = blockIdx.x;
  while (chunk < NCHUNK) {
    const int b = chunk >> 7, j = chunk & 127;
    const int vn = event_nums[b];
    if (j < vn) {
      unsigned* eblk = eg + (size_t)(b*128 + j) * 8192;
      float bLv[4], bMv[4];
      #pragma unroll
      for (int ct = 0; ct < 4; ++ct) {
        int c = colg[ct];
        bLv[ct] = b_l[(size_t)(b*128 + j)*128 + c] + bl1[c];
        bMv[ct] = b_m[(size_t)(b*128 + j)*128 + c] + bm[c];
      }
      if (t < 128) msum[t] = 0.f;
      const int nhalf = (vn > 64) ? 2 : 1;
      for (int hh = 0; hh < nhalf; ++hh) {
        const int row0 = hh*64;
        int vnl = vn - row0; if (vnl > 64) vnl = 64;
        int nvt = (vnl - rh2*32 + 15) >> 4;
        nvt = nvt < 0 ? 0 : (nvt > 2 ? 2 : nvt);

        if (t < 64) {
          adj[t] = 0.f;
          id_s[t] = ids[((size_t)(b*128 + row0 + t))*128 + j];
        }
        // Prefetch a_l / a_m into registers (hide L2/L3 latency under barrier)
        const float* aLb = a_l + (size_t)(b*128 + row0)*128;
        const float* aMb = a_m + (size_t)(b*128 + row0)*128;
        float alv[2][4][4], amv[2][4][4];
        #pragma unroll
        for (int rt = 0; rt < 2; ++rt)
          if (rt < nvt) {
            #pragma unroll
            for (int ct = 0; ct < 4; ++ct)
              #pragma unroll
              for (int r = 0; r < 4; ++r) {
                int lrow = rh2*32 + rt*16 + q*4 + r;
                alv[rt][ct][r] = aLb[(size_t)lrow*128 + colg[ct]];
                amv[rt][ct][r] = aMb[(size_t)lrow*128 + colg[ct]];
              }
          }
        __syncthreads();   // B1: id_s/adj (+tabs on first pass) ready

        // Z epilogue from tables
        #pragma unroll
        for (int rt = 0; rt < 2; ++rt) {
          if (rt < nvt) {
            float szr[4] = {0.f,0.f,0.f,0.f};
            #pragma unroll
            for (int ct = 0; ct < 4; ++ct) {
              #pragma unroll
              for (int r = 0; r < 4; ++r) {
                int lrow = rh2*32 + rt*16 + q*4 + r;
                float zv = fmaxf(tabZ[id_s[lrow]*128 + colg[ct]] + alv[rt][ct][r] + bLv[ct], 0.f);
                szr[r] += zv * wl2v[ct];
              }
            }
            #pragma unroll
            for (int r = 0; r < 4; ++r) {
              szr[r] += __shfl_xor(szr[r], 1);
              szr[r] += __shfl_xor(szr[r], 2);
              szr[r] += __shfl_xor(szr[r], 4);
              szr[r] += __shfl_xor(szr[r], 8);
            }
            if (n == 0) {
              #pragma unroll
              for (int r = 0; r < 4; ++r)
                atomicAdd(&adj[rh2*32 + rt*16 + q*4 + r], szr[r]);
            }
          }
        }
        __syncthreads();   // B2: adj final

        // M epilogue from tables -> m16, msum (per-thread sigmoid)
        {
          float colsum[4] = {0.f,0.f,0.f,0.f};
          #pragma unroll
          for (int rt = 0; rt < 2; ++rt) {
            if (rt < nvt) {
              #pragma unroll
              for (int r = 0; r < 4; ++r) {
                int lrow = rh2*32 + rt*16 + q*4 + r;
                float sc = (lrow < vnl) ? sigf(adj[lrow] + bl2v) : 0.f;
                #pragma unroll
                for (int ct = 0; ct < 4; ++ct) {
                  float mv = fmaxf(tabM[id_s[lrow]*128 + colg[ct]] + amv[rt][ct][r] + bMv[ct], 0.f) * sc;
                  m16[lrow*136 + colg[ct]] = bf16_1(mv);
                  colsum[ct] += mv;
                }
              }
            }
          }
          #pragma unroll
          for (int ct = 0; ct < 4; ++ct) {
            float v = colsum[ct];
            v += __shfl_xor(v, 16);
            v += __shfl_xor(v, 32);
            if (lane < 16) atomicAdd(&msum[colg[ct]], v);
          }
        }
        __syncthreads();   // B3: m16/msum final

        // U = tabU gather + M@Wu_m
        floatx4 au[2][4];
        #pragma unroll
        for (int rt = 0; rt < 2; ++rt)
          #pragma unroll
          for (int ct = 0; ct < 4; ++ct) {
            au[rt][ct] = (floatx4){0.f,0.f,0.f,0.f};
            if (rt < nvt) {
              #pragma unroll
              for (int r = 0; r < 4; ++r) {
                int lrow = rh2*32 + rt*16 + q*4 + r;
                au[rt][ct][r] = tabU[id_s[lrow]*128 + colg[ct]];
              }
            }
          }
        MFMA_HALF(m_a, wum, au, 0)
        MFMA_HALF(m_a, wum, au, 2)
        __syncthreads();   // B4: done reading m_a

        #pragma unroll
        for (int rt = 0; rt < 2; ++rt)
          if (rt < nvt) {
            #pragma unroll
            for (int ct = 0; ct < 4; ++ct)
              #pragma unroll
              for (int r = 0; r < 4; ++r) {
                int lrow = rh2*32 + rt*16 + q*4 + r;
                m16[lrow*136 + colg[ct]] = bf16_1(fmaxf(au[rt][ct][r] + buv[ct], 0.f));
              }
          }
        __syncthreads();   // B5: m16 final
        #pragma unroll
        for (int it = 0; it < 4; ++it) {
          int f = it*256 + t;
          int lr = f >> 4, c4 = (f & 15) * 4;
          if (row0 + lr < vn)
            *(uint4*)&eblk[(size_t)(row0 + lr)*64 + c4] = *(const uint4*)&m_a[lr*68 + c4];
        }
      }
      if (t < 128) ms[(size_t)(b*128 + j)*128 + t] = msum[t];   // exclusive owner
    }
    if (t == 0) task_s = (int)atomicAdd(qc, 1u);
    __syncthreads();
    chunk = task_s;
    __syncthreads();
  }
}

// ---------- edge rounds >=1: persistent blocks, LDS-staged E (R1 structure) ----------
__global__ __launch_bounds__(256,4) void edge_round_rest(
  unsigned* __restrict__ eg,
  const unsigned* __restrict__ wT,
  const float* __restrict__ a_l, const float* __restrict__ b_l,
  const float* __restrict__ a_m, const float* __restrict__ b_m,
  const float* __restrict__ bl1, const float* __restrict__ wl2,
  const float* __restrict__ bl2, const float* __restrict__ bm,
  const float* __restrict__ bu,
  const int* __restrict__ event_nums,
  float* __restrict__ ms, unsigned* __restrict__ qc)
{
  __shared__ unsigned e_s[64*68];
  __shared__ unsigned m_a[64*68];
  __shared__ float adj[64], msum[128];
  __shared__ int task_s;
  unsigned short* m16 = (unsigned short*)m_a;

  const int t = threadIdx.x;
  const int lane = t & 63, wv = t >> 6;
  const int q = lane >> 4, n = lane & 15;
  const int rh2 = wv >> 1, ch = wv & 1;
  int colg[4];
  #pragma unroll
  for (int ct = 0; ct < 4; ++ct) colg[ct] = ch*64 + ct*16 + n;
  int arowi[2];
  #pragma unroll
  for (int rt = 0; rt < 2; ++rt) arowi[rt] = rh2*32 + rt*16 + n;

  const unsigned* wz  = wT;
  const unsigned* wm  = wT + 8192;
  const unsigned* wue = wT + 16384;
  const unsigned* wum = wT + 24576;
  const float bl2v = bl2[0];
  float wl2v[4], buv[4];
  #pragma unroll
  for (int ct = 0; ct < 4; ++ct) { wl2v[ct] = wl2[colg[ct]]; buv[ct] = bu[colg[ct]]; }

  int chunk = blockIdx.x;
  while (chunk < NCHUNK) {
    const int b = chunk >> 7, j = chunk & 127;
    const int vn = event_nums[b];
    if (j < vn) {
      unsigned* eblk = eg + (size_t)(b*128 + j) * 8192;
      float bLv[4], bMv[4];
      #pragma unroll
      for (int ct = 0; ct < 4; ++ct) {
        int c = colg[ct];
        bLv[ct] = b_l[(size_t)(b*128 + j)*128 + c] + bl1[c];
        bMv[ct] = b_m[(size_t)(b*128 + j)*128 + c] + bm[c];
      }
      if (t < 128) msum[t] = 0.f;
      const int nhalf = (vn > 64) ? 2 : 1;
      for (int hh = 0; hh < nhalf; ++hh) {
        const int row0 = hh*64;
        int vnl = vn - row0; if (vnl > 64) vnl = 64;
        int nvt = (vnl - rh2*32 + 15) >> 4;
        nvt = nvt < 0 ? 0 : (nvt > 2 ? 2 : nvt);

        if (t < 64) adj[t] = 0.f;
        // stage E tile -> LDS (coalesced 16B per thread)
        {
          const int vnc16 = (vnl + 15) & ~15;
          const int srow = t >> 4, c4 = (t & 15) * 4;
          #pragma unroll
          for (int it = 0; it < 4; ++it) {
            int lr = it*16 + srow;
            if (lr < vnc16)
              *(uint4*)&e_s[lr*68 + c4] = *(const uint4*)&eblk[(size_t)(row0 + lr)*64 + c4];
          }
        }
        // Prefetch a_l pre-B1: latency hides under staging
        const float* aLb = a_l + (size_t)(b*128 + row0)*128;
        const float* aMb = a_m + (size_t)(b*128 + row0)*128;
        float alv[2][4][4];
        #pragma unroll
        for (int rt = 0; rt < 2; ++rt)
          if (rt < nvt) {
            #pragma unroll
            for (int ct = 0; ct < 4; ++ct)
              #pragma unroll
              for (int r = 0; r < 4; ++r)
                alv[rt][ct][r] = aLb[(size_t)(rh2*32 + rt*16 + q*4 + r)*128 + colg[ct]];
          }
        __syncthreads();   // B1: e_s staged, adj zero

        // ---------- PASS Z ----------
        floatx4 az[2][4];
        #pragma unroll
        for (int rt = 0; rt < 2; ++rt)
          #pragma unroll
          for (int ct = 0; ct < 4; ++ct) az[rt][ct] = (floatx4){0.f,0.f,0.f,0.f};
        MFMA_HALF(e_s, wz, az, 0)
        MFMA_HALF(e_s, wz, az, 2)

        // Z epilogue (consume prefetched alv)
        #pragma unroll
        for (int rt = 0; rt < 2; ++rt) {
          if (rt < nvt) {
            float szr[4] = {0.f,0.f,0.f,0.f};
            #pragma unroll
            for (int ct = 0; ct < 4; ++ct) {
              #pragma unroll
              for (int r = 0; r < 4; ++r) {
                float zv = fmaxf(az[rt][ct][r] + alv[rt][ct][r] + bLv[ct], 0.f);
                szr[r] += zv * wl2v[ct];
              }
            }
            #pragma unroll
            for (int r = 0; r < 4; ++r) {
              szr[r] += __shfl_xor(szr[r], 1);
              szr[r] += __shfl_xor(szr[r], 2);
              szr[r] += __shfl_xor(szr[r], 4);
              szr[r] += __shfl_xor(szr[r], 8);
            }
            if (n == 0) {
              #pragma unroll
              for (int r = 0; r < 4; ++r)
                atomicAdd(&adj[rh2*32 + rt*16 + q*4 + r], szr[r]);
            }
          }
        }

        // Prefetch a_m (alv dead): hides under B2 + M MFMA
        float amv[2][4][4];
        #pragma unroll
        for (int rt = 0; rt < 2; ++rt)
          if (rt < nvt) {
            #pragma unroll
            for (int ct = 0; ct < 4; ++ct)
              #pragma unroll
              for (int r = 0; r < 4; ++r)
                amv[rt][ct][r] = aMb[(size_t)(rh2*32 + rt*16 + q*4 + r)*128 + colg[ct]];
          }
        __syncthreads();   // B2: adj final

        // ---------- PASS M ----------
        floatx4 am[2][4];
        #pragma unroll
        for (int rt = 0; rt < 2; ++rt)
          #pragma unroll
          for (int ct = 0; ct < 4; ++ct) am[rt][ct] = (floatx4){0.f,0.f,0.f,0.f};
        MFMA_HALF(e_s, wm, am, 0)
        MFMA_HALF(e_s, wm, am, 2)

        // M epilogue (per-thread sigmoid)
        {
          float colsum[4] = {0.f,0.f,0.f,0.f};
          #pragma unroll
          for (int rt = 0; rt < 2; ++rt) {
            if (rt < nvt) {
              #pragma unroll
              for (int r = 0; r < 4; ++r) {
                int lrow = rh2*32 + rt*16 + q*4 + r;
                float sc = (lrow < vnl) ? sigf(adj[lrow] + bl2v) : 0.f;
                #pragma unroll
                for (int ct = 0; ct < 4; ++ct) {
                  float mv = fmaxf(am[rt][ct][r] + amv[rt][ct][r] + bMv[ct], 0.f) * sc;
                  m16[lrow*136 + colg[ct]] = bf16_1(mv);
                  colsum[ct] += mv;
                }
              }
            }
          }
          #pragma unroll
          for (int ct = 0; ct < 4; ++ct) {
            float v = colsum[ct];
            v += __shfl_xor(v, 16);
            v += __shfl_xor(v, 32);
            if (lane < 16) atomicAdd(&msum[colg[ct]], v);
          }
        }
        __syncthreads();   // B3: m16/msum final

        // ---------- PASS U ----------
        floatx4 au[2][4];
        #pragma unroll
        for (int rt = 0; rt < 2; ++rt)
          #pragma unroll
          for (int ct = 0; ct < 4; ++ct) au[rt][ct] = (floatx4){0.f,0.f,0.f,0.f};
        MFMA_HALF(e_s, wue, au, 0)
        MFMA_HALF(e_s, wue, au, 2)
        MFMA_HALF(m_a, wum, au, 0)
        MFMA_HALF(m_a, wum, au, 2)
        __syncthreads();   // B4: done reading m_a & e_s

        #pragma unroll
        for (int rt = 0; rt < 2; ++rt)
          if (rt < nvt) {
            #pragma unroll
            for (int ct = 0; ct < 4; ++ct)
              #pragma unroll
              for (int r = 0; r < 4; ++r) {
                int lrow = rh2*32 + rt*16 + q*4 + r;
                m16[lrow*136 + colg[ct]] = bf16_1(fmaxf(au[rt][ct][r] + buv[ct], 0.f));
              }
          }
        __syncthreads();   // B5: m16 final
        #pragma unroll
        for (int it = 0; it < 4; ++it) {
          int f = it*256 + t;
          int lr = f >> 4, c4 = (f & 15) * 4;
          if (row0 + lr < vn)
            *(uint4*)&eblk[(size_t)(row0 + lr)*64 + c4] = *(const uint4*)&m_a[lr*68 + c4];
        }
      }
      if (t < 128) ms[(size_t)(b*128 + j)*128 + t] = msum[t];   // exclusive owner
    }
    if (t == 0) task_s = (int)atomicAdd(qc, 1u);
    __syncthreads();
    chunk = task_s;
    __syncthreads();
  }
}

// ---------- MFMA readout, both GEMMs on matrix cores ----------
__global__ __launch_bounds__(256,4) void readout_mfma(
  const unsigned* __restrict__ eg,
  const unsigned* __restrict__ wr1T,
  const unsigned* __restrict__ wr2T,
  const float* __restrict__ br1, const float* __restrict__ br2,
  const int* __restrict__ event_nums, float* __restrict__ out)
{
  __shared__ unsigned f_s[64*132];
  __shared__ int iu_s[64], ju_s[64];
  unsigned short* h16 = (unsigned short*)f_s;

  const int t = threadIdx.x;
  const int b = blockIdx.x / 127, pb = blockIdx.x % 127;
  const int vn = event_nums[b];

  if (t < 64) {
    int p = pb*64 + t;
    float disc = (float)((2*NN-1)*(2*NN-1) - 8*p);
    int iu = (int)(((float)(2*NN-1) - sqrtf(disc)) * 0.5f);
    if (iu < 0) iu = 0; if (iu > NN-2) iu = NN-2;
    while (iu < NN-2 && ((iu+1)*(2*NN-2-iu))/2 <= p) ++iu;
    while (iu > 0 && (iu*(2*NN-1-iu))/2 > p) --iu;
    int ju = p - (iu*(2*NN-1-iu))/2 + iu + 1;
    iu_s[t] = iu; ju_s[t] = ju;
  }
  __syncthreads();

  #pragma unroll
  for (int it = 0; it < 8; ++it) {
    int f4 = it*1024 + t*4;
    int pr = f4 >> 7, w = f4 & 127;
    int side = w >> 6, k2 = w & 63;
    int iu = iu_s[pr], ju = ju_s[pr];
    size_t base = side ? (((size_t)(b*128 + iu))*128 + ju)*64
                       : (((size_t)(b*128 + ju))*128 + iu)*64;
    *(uint4*)&f_s[pr*132 + w] = *(const uint4*)&eg[base + k2];
  }
  __syncthreads();

  const int lane = t & 63, wv = t >> 6;
  const int q = lane >> 4, n = lane & 15;
  int colg[4];
  #pragma unroll
  for (int ct = 0; ct < 4; ++ct) colg[ct] = wv*64 + ct*16 + n;

  floatx4 acc[4][4];
  #pragma unroll
  for (int rt = 0; rt < 4; ++rt)
    #pragma unroll
    for (int ct = 0; ct < 4; ++ct) acc[rt][ct] = (floatx4){0.f,0.f,0.f,0.f};

  #pragma unroll
  for (int kb = 0; kb < 8; ++kb) {
    uint4 bb[4];
    #pragma unroll
    for (int ct = 0; ct < 4; ++ct) bb[ct] = *(const uint4*)(wr1T + (size_t)colg[ct]*128 + kb*16 + q*4);
    #pragma unroll
    for (int rt = 0; rt < 4; ++rt) {
      uint4 a = *(const uint4*)&f_s[(rt*16 + n)*132 + kb*16 + q*4];
      #pragma unroll
      for (int ct = 0; ct < 4; ++ct)
        acc[rt][ct] = __builtin_amdgcn_mfma_f32_16x16x32_bf16(as_s8(a), as_s8(bb[ct]), acc[rt][ct], 0, 0, 0);
    }
  }
  __syncthreads();

  {
    float brv[4];
    #pragma unroll
    for (int ct = 0; ct < 4; ++ct) brv[ct] = br1[colg[ct]];
    #pragma unroll
    for (int rt = 0; rt < 4; ++rt)
      #pragma unroll
      for (int ct = 0; ct < 4; ++ct)
        #pragma unroll
        for (int r = 0; r < 4; ++r) {
          int pr = rt*16 + q*4 + r;
          h16[pr*264 + colg[ct]] = bf16_1(fmaxf(acc[rt][ct][r] + brv[ct], 0.f));
        }
  }
  __syncthreads();

  floatx4 acc2 = (floatx4){0.f,0.f,0.f,0.f};
  #pragma unroll
  for (int kb = 0; kb < 8; ++kb) {
    uint4 bb = *(const uint4*)(wr2T + n*128 + kb*16 + q*4);
    uint4 a  = *(const uint4*)&f_s[(wv*16 + n)*132 + kb*16 + q*4];
    acc2 = __builtin_amdgcn_mfma_f32_16x16x32_bf16(as_s8(a), as_s8(bb), acc2, 0, 0, 0);
  }

  if (n < 10) {
    float bias = br2[n];
    #pragma unroll
    for (int r = 0; r < 4; ++r) {
      int pr = wv*16 + q*4 + r;
      int iu = iu_s[pr], ju = ju_s[pr];
      if (ju < vn) {
        int idx = iu*vn - (iu*(iu+1))/2 + (ju - iu - 1);
        out[(((size_t)b*5 + (n>>1))*PP + idx)*2 + (n&1)] = acc2[r] + bias;
      }
    }
  }
}

extern "C" void kernel_launch(void* const* d_in, const int* in_sizes, int n_in,
                              void* d_out, int out_size, void* d_ws, size_t ws_size,
                              hipStream_t stream) {
  const int*   edge_ids      = (const int*)d_in[0];
  const float* node_features = (const float*)d_in[1];
  const int*   event_nums    = (const int*)d_in[3];
  const float* emb  = (const float*)d_in[4];
  const float* Wl_e = (const float*)d_in[5];
  const float* Wl_w = (const float*)d_in[6];
  const float* Wl_v = (const float*)d_in[7];
  const float* bl1  = (const float*)d_in[8];
  const float* wl2  = (const float*)d_in[9];
  const float* bl2  = (const float*)d_in[10];
  const float* Wm_w = (const float*)d_in[11];
  const float* Wm_v = (const float*)d_in[12];
  const float* Wm_e = (const float*)d_in[13];
  const float* bm   = (const float*)d_in[14];
  const float* Wu_e = (const float*)d_in[15];
  const float* Wu_m = (const float*)d_in[16];
  const float* bu   = (const float*)d_in[17];
  const float* W_ih = (const float*)d_in[18];
  const float* W_hh = (const float*)d_in[19];
  const float* b_ih = (const float*)d_in[20];
  const float* b_hh = (const float*)d_in[21];
  const float* Wr1  = (const float*)d_in[22];
  const float* br1  = (const float*)d_in[23];
  const float* Wr2  = (const float*)d_in[24];
  const float* br2  = (const float*)d_in[25];

  const size_t SZ_E = (size_t)134217728;       // B*N*N*64 u32
  const size_t SZ_S = (size_t)2097152;         // B*N*128 f32
  const size_t SZ_W = (size_t)131072;          // 32768 u32
  const size_t SZ_W2 = (size_t)8192;           // 2048 u32
  const size_t SZ_TAB = (size_t)2048;          // 512 f32 each
  const size_t SZ_Q = (size_t)64;              // 16 u32 task counters
  const size_t need = SZ_E + 6*SZ_S + 2*SZ_W + SZ_W2 + 3*SZ_TAB + SZ_Q;

  hipMemsetAsync(d_out, 0, (size_t)out_size * sizeof(float), stream);
  if (ws_size < need) return;

  char* w = (char*)d_ws;
  unsigned* eg   = (unsigned*)w; w += SZ_E;
  float* h_ws = (float*)w; w += SZ_S;
  float* a_l  = (float*)w; w += SZ_S;
  float* b_l  = (float*)w; w += SZ_S;
  float* a_m  = (float*)w; w += SZ_S;
  float* b_m  = (float*)w; w += SZ_S;
  float* ms   = (float*)w; w += SZ_S;
  unsigned* wT   = (unsigned*)w; w += SZ_W;
  unsigned* wr1T = (unsigned*)w; w += SZ_W;
  unsigned* wr2T = (unsigned*)w; w += SZ_W2;
  float* embZ = (float*)w; w += SZ_TAB;
  float* embM = (float*)w; w += SZ_TAB;
  float* embU = (float*)w; w += SZ_TAB;
  unsigned* qctr = (unsigned*)w; w += SZ_Q;

  hipLaunchKernelGGL(conv_w_kernel, dim3(256), dim3(256), 0, stream,
      Wl_e, Wm_e, Wu_e, Wu_m, Wr1, Wr2, emb, wT, wr1T, wr2T, embZ, embM, embU, qctr);

  hipLaunchKernelGGL(gru_proj_kernel, dim3(1024), dim3(256), 0, stream,
      0, ms, node_features, h_ws, W_ih, W_hh, b_ih, b_hh,
      Wl_w, Wl_v, Wm_w, Wm_v, event_nums, a_l, b_l, a_m, b_m);

  for (int r = 0; r < 3; ++r) {
    if (r == 0) {
      hipLaunchKernelGGL(edge_round_first, dim3(QGRID), dim3(256), 0, stream,
          eg, wT, edge_ids, embZ, embM, embU,
          a_l, b_l, a_m, b_m, bl1, wl2, bl2, bm, bu, event_nums, ms, qctr + 0);
    } else {
      hipLaunchKernelGGL(edge_round_rest, dim3(QGRID), dim3(256), 0, stream,
          eg, wT, a_l, b_l, a_m, b_m, bl1, wl2, bl2, bm, bu, event_nums, ms, qctr + r);
    }
    if (r < 2) {
      const float* hin = (r == 0) ? node_features : h_ws;
      hipLaunchKernelGGL(gru_proj_kernel, dim3(1024), dim3(256), 0, stream,
          1, ms, hin, h_ws, W_ih, W_hh, b_ih, b_hh,
          Wl_w, Wl_v, Wm_w, Wm_v, event_nums, a_l, b_l, a_m, b_m);
    }
  }

  hipLaunchKernelGGL(readout_mfma, dim3(BB*127), dim3(256), 0, stream,
      eg, wr1T, wr2T, br1, br2, event_nums, (float*)d_out);
}

// Round 4
// 1848.802 us; speedup vs baseline: 1.3026x; 1.1178x over previous
//
#include <hip/hip_runtime.h>
#include <cstddef>

// Problem constants
#define BB 32
#define NN 128
#define PP 8128
#define NCHUNK 4096      // 32 b * 128 j
#define QGRID 1024       // persistent blocks (256 CU * 4 resident)

typedef __attribute__((ext_vector_type(8))) short short8;
typedef __attribute__((ext_vector_type(4))) float floatx4;

union U4S8 { uint4 u; short8 s; };
__device__ __forceinline__ short8 as_s8(uint4 v){ U4S8 x; x.u = v; return x.s; }

// ---------- bf16 helpers ----------
__device__ __forceinline__ unsigned pack_bf16(float a, float b){
  union{float f;unsigned u;}xa,xb; xa.f=a; xb.f=b;
  unsigned ua=xa.u, ub=xb.u;
  ua = (ua + 0x7fffu + ((ua>>16)&1u)) >> 16;
  ub = (ub + 0x7fffu + ((ub>>16)&1u)) >> 16;
  return (ua & 0xffffu) | (ub << 16);
}
__device__ __forceinline__ unsigned short bf16_1(float a){
  union{float f;unsigned u;}x; x.f=a;
  return (unsigned short)((x.u + 0x7fffu + ((x.u>>16)&1u)) >> 16);
}
__device__ __forceinline__ float sigf(float x){ return 1.f/(1.f + __expf(-x)); }

// ---------- weight conversion + round-0 tables + queue-counter init ----------
__global__ __launch_bounds__(256,4) void conv_w_kernel(
  const float* __restrict__ Wl_e, const float* __restrict__ Wm_e,
  const float* __restrict__ Wu_e, const float* __restrict__ Wu_m,
  const float* __restrict__ Wr1, const float* __restrict__ Wr2,
  const float* __restrict__ emb,
  unsigned* __restrict__ wT, unsigned* __restrict__ wr1T,
  unsigned* __restrict__ wr2T,
  float* __restrict__ embZ, float* __restrict__ embM, float* __restrict__ embU,
  unsigned* __restrict__ qctr)
{
  int tid = blockIdx.x*256 + threadIdx.x;   // 65536 total
  if (tid < 16) qctr[tid] = QGRID;          // reset per-round task counters each launch
  if (tid < 2048) {   // Wr2 [256][10] -> B-frag layout [16 cols][128 k2], zero-padded
    int c = tid >> 7, k2 = tid & 127;
    unsigned v = 0;
    if (c < 10) v = pack_bf16(Wr2[(2*k2)*10 + c], Wr2[(2*k2+1)*10 + c]);
    wr2T[c*128 + k2] = v;
  }
  if (tid >= 4096 && tid < 5632) {   // round-0 tables: emb(4x128) @ W(128x128), f32
    int idx = tid - 4096;            // 0..1535
    int tb = idx >> 9;               // 0..2
    int r  = idx & 511;
    int id = r >> 7, c = r & 127;
    const float* W = (tb==0) ? Wl_e : (tb==1) ? Wm_e : Wu_e;
    float s = 0.f;
    #pragma unroll 4
    for (int k = 0; k < 128; ++k) s += emb[id*128 + k] * W[(size_t)k*128 + c];
    float* T = (tb==0) ? embZ : (tb==1) ? embM : embU;
    T[r] = s;
  }
  if (tid < 32768) {
    int mat = tid >> 13, r = tid & 8191;
    int k2 = r >> 7, c = r & 127;
    const float* W = (mat==0) ? Wl_e : (mat==1) ? Wm_e : (mat==2) ? Wu_e : Wu_m;
    wT[mat*8192 + c*64 + k2] = pack_bf16(W[(2*k2)*128 + c], W[(2*k2+1)*128 + c]);
  } else {
    int r = tid - 32768;
    int k2 = r >> 8, c = r & 255;
    wr1T[(size_t)c*128 + k2] = pack_bf16(Wr1[(2*k2)*256 + c], Wr1[(2*k2+1)*256 + c]);
  }
}

// ---------- fused GRU + node projections ----------
__global__ __launch_bounds__(256,4) void gru_proj_kernel(
  int do_gru,
  const float* __restrict__ ms, const float* __restrict__ h_in, float* __restrict__ h_out,
  const float* __restrict__ W_ih, const float* __restrict__ W_hh,
  const float* __restrict__ b_ih, const float* __restrict__ b_hh,
  const float* __restrict__ Wl_w, const float* __restrict__ Wl_v,
  const float* __restrict__ Wm_w, const float* __restrict__ Wm_v,
  const int* __restrict__ event_nums,
  float* __restrict__ a_l, float* __restrict__ b_l,
  float* __restrict__ a_m, float* __restrict__ b_m)
{
  __shared__ float h_s[4][128];
  __shared__ float ms_s[4][128];
  const int t = threadIdx.x, blk = blockIdx.x;
  const int b = blk >> 5, n0 = (blk & 31) * 4;
  const int vn = event_nums[b];
  const int g = t >> 6, l = t & 63;
  const int row = b*128 + n0 + g;

  h_s[g][l]    = h_in[(size_t)row*128 + l];
  h_s[g][l+64] = h_in[(size_t)row*128 + l + 64];
  if (do_gru) {
    ms_s[g][l]    = ms[(size_t)row*128 + l];
    ms_s[g][l+64] = ms[(size_t)row*128 + l + 64];
  }
  __syncthreads();

  if (do_gru) {
    float acc[12] = {};
    #pragma unroll 4
    for (int k = 0; k < 128; ++k) {
      float mv = ms_s[g][k], hv = h_s[g][k];
      #pragma unroll
      for (int u = 0; u < 6; ++u) {
        acc[u]   += mv * W_ih[(size_t)k*384 + l + 64*u];
        acc[6+u] += hv * W_hh[(size_t)k*384 + l + 64*u];
      }
    }
    const bool valid = (n0 + g) < vn;
    float hnew[2];
    #pragma unroll
    for (int u = 0; u < 2; ++u) {
      int c = l + 64*u;
      float ir = acc[u]     + b_ih[c];
      float iz = acc[u+2]   + b_ih[128+c];
      float in_= acc[u+4]   + b_ih[256+c];
      float hr = acc[6+u]   + b_hh[c];
      float hz = acc[8+u]   + b_hh[128+c];
      float hn = acc[10+u]  + b_hh[256+c];
      float r  = sigf(ir + hr);
      float zg = sigf(iz + hz);
      float nn = tanhf(in_ + r*hn);
      float hold = h_s[g][c];
      hnew[u] = valid ? (1.f - zg)*nn + zg*hold : hold;
    }
    __syncthreads();
    #pragma unroll
    for (int u = 0; u < 2; ++u) {
      int c = l + 64*u;
      h_s[g][c] = hnew[u];
      h_out[(size_t)row*128 + c] = hnew[u];
    }
    __syncthreads();
  }

  {
    const float* Wp[4] = {Wl_w, Wl_v, Wm_w, Wm_v};
    float* Op[4] = {a_l, b_l, a_m, b_m};
    float acc2[8] = {};
    #pragma unroll 4
    for (int k = 0; k < 128; ++k) {
      float hv = h_s[g][k];
      #pragma unroll
      for (int u = 0; u < 8; ++u)
        acc2[u] += hv * Wp[u>>1][(size_t)k*128 + l + 64*(u&1)];
    }
    #pragma unroll
    for (int u = 0; u < 8; ++u)
      Op[u>>1][(size_t)row*128 + l + 64*(u&1)] = acc2[u];
  }
}

// MFMA half-pass helper: A-fragments from an LDS tile (stride 68 u32 per row)
#define MFMA_HALF(SRC, WPTR, ACC, KB0)                                           \
  {                                                                              \
    uint4 bb[2][4];                                                              \
    _Pragma("unroll")                                                            \
    for (int k2 = 0; k2 < 2; ++k2)                                               \
      _Pragma("unroll")                                                          \
      for (int ct = 0; ct < 4; ++ct)                                             \
        bb[k2][ct] = *(const uint4*)((WPTR) + colg[ct]*64 + ((KB0)+k2)*16 + q*4);\
    _Pragma("unroll")                                                            \
    for (int k2 = 0; k2 < 2; ++k2)                                               \
      _Pragma("unroll")                                                          \
      for (int rt = 0; rt < 2; ++rt)                                             \
        if (rt < nvt) {                                                          \
          uint4 a = *(const uint4*)&SRC[arowi[rt]*68 + ((KB0)+k2)*16 + q*4];     \
          _Pragma("unroll")                                                      \
          for (int ct = 0; ct < 4; ++ct)                                         \
            ACC[rt][ct] = __builtin_amdgcn_mfma_f32_16x16x32_bf16(               \
              as_s8(a), as_s8(bb[k2][ct]), ACC[rt][ct], 0,0,0);                  \
        }                                                                        \
  }

// ---------- edge round 0: table-driven, persistent blocks, dynamic queue ----------
// Lean body: a_l/a_m loaded inline in epilogues (no prefetch arrays -> no spill).
__global__ __launch_bounds__(256,4) void edge_round_first(
  unsigned* __restrict__ eg,
  const unsigned* __restrict__ wT,
  const int* __restrict__ ids,
  const float* __restrict__ embZ, const float* __restrict__ embM,
  const float* __restrict__ embU,
  const float* __restrict__ a_l, const float* __restrict__ b_l,
  const float* __restrict__ a_m, const float* __restrict__ b_m,
  const float* __restrict__ bl1, const float* __restrict__ wl2,
  const float* __restrict__ bl2, const float* __restrict__ bm,
  const float* __restrict__ bu,
  const int* __restrict__ event_nums,
  float* __restrict__ ms, unsigned* __restrict__ qc)
{
  __shared__ unsigned m_a[64*68];
  __shared__ float adj[64], msum[128];
  __shared__ float tabZ[512], tabM[512], tabU[512];
  __shared__ int id_s[64];
  __shared__ int task_s;
  unsigned short* m16 = (unsigned short*)m_a;

  const int t = threadIdx.x;
  const int lane = t & 63, wv = t >> 6;
  const int q = lane >> 4, n = lane & 15;
  const int rh2 = wv >> 1, ch = wv & 1;
  int colg[4];
  #pragma unroll
  for (int ct = 0; ct < 4; ++ct) colg[ct] = ch*64 + ct*16 + n;
  int arowi[2];
  #pragma unroll
  for (int rt = 0; rt < 2; ++rt) arowi[rt] = rh2*32 + rt*16 + n;
  const unsigned* wum = wT + 24576;
  const float bl2v = bl2[0];

  for (int i = t; i < 512; i += 256) {
    tabZ[i] = embZ[i]; tabM[i] = embM[i]; tabU[i] = embU[i];
  }
  // first use of tabs is after B1 inside the loop — that barrier publishes them

  int chunk = blockIdx.x;
  while (chunk < NCHUNK) {
    const int b = chunk >> 7, j = chunk & 127;
    const int vn = event_nums[b];
    if (j < vn) {
      unsigned* eblk = eg + (size_t)(b*128 + j) * 8192;
      if (t < 128) msum[t] = 0.f;
      const int nhalf = (vn > 64) ? 2 : 1;
      for (int hh = 0; hh < nhalf; ++hh) {
        const int row0 = hh*64;
        int vnl = vn - row0; if (vnl > 64) vnl = 64;
        int nvt = (vnl - rh2*32 + 15) >> 4;
        nvt = nvt < 0 ? 0 : (nvt > 2 ? 2 : nvt);

        if (t < 64) {
          adj[t] = 0.f;
          id_s[t] = ids[((size_t)(b*128 + row0 + t))*128 + j];
        }
        __syncthreads();   // B1: id_s/adj (+tabs on first pass, msum at chunk top) ready

        // Z epilogue from tables (a_l inline)
        {
          float wl2v[4], bLv[4];
          #pragma unroll
          for (int ct = 0; ct < 4; ++ct) {
            int c = colg[ct];
            wl2v[ct] = wl2[c];
            bLv[ct]  = b_l[(size_t)(b*128 + j)*128 + c] + bl1[c];
          }
          const float* aLb = a_l + (size_t)(b*128 + row0)*128;
          #pragma unroll
          for (int rt = 0; rt < 2; ++rt) {
            if (rt < nvt) {
              float szr[4] = {0.f,0.f,0.f,0.f};
              #pragma unroll
              for (int ct = 0; ct < 4; ++ct) {
                #pragma unroll
                for (int r = 0; r < 4; ++r) {
                  int lrow = rh2*32 + rt*16 + q*4 + r;
                  float zv = fmaxf(tabZ[id_s[lrow]*128 + colg[ct]]
                                   + aLb[(size_t)lrow*128 + colg[ct]] + bLv[ct], 0.f);
                  szr[r] += zv * wl2v[ct];
                }
              }
              #pragma unroll
              for (int r = 0; r < 4; ++r) {
                szr[r] += __shfl_xor(szr[r], 1);
                szr[r] += __shfl_xor(szr[r], 2);
                szr[r] += __shfl_xor(szr[r], 4);
                szr[r] += __shfl_xor(szr[r], 8);
              }
              if (n == 0) {
                #pragma unroll
                for (int r = 0; r < 4; ++r)
                  atomicAdd(&adj[rh2*32 + rt*16 + q*4 + r], szr[r]);
              }
            }
          }
        }
        __syncthreads();   // B2: adj final

        // M epilogue from tables -> m16, msum (a_m inline, per-thread sigmoid)
        {
          float bMv[4];
          #pragma unroll
          for (int ct = 0; ct < 4; ++ct) {
            int c = colg[ct];
            bMv[ct] = b_m[(size_t)(b*128 + j)*128 + c] + bm[c];
          }
          const float* aMb = a_m + (size_t)(b*128 + row0)*128;
          float colsum[4] = {0.f,0.f,0.f,0.f};
          #pragma unroll
          for (int rt = 0; rt < 2; ++rt) {
            if (rt < nvt) {
              #pragma unroll
              for (int r = 0; r < 4; ++r) {
                int lrow = rh2*32 + rt*16 + q*4 + r;
                float sc = (lrow < vnl) ? sigf(adj[lrow] + bl2v) : 0.f;
                #pragma unroll
                for (int ct = 0; ct < 4; ++ct) {
                  float mv = fmaxf(tabM[id_s[lrow]*128 + colg[ct]]
                                   + aMb[(size_t)lrow*128 + colg[ct]] + bMv[ct], 0.f) * sc;
                  m16[lrow*136 + colg[ct]] = bf16_1(mv);
                  colsum[ct] += mv;
                }
              }
            }
          }
          #pragma unroll
          for (int ct = 0; ct < 4; ++ct) {
            float v = colsum[ct];
            v += __shfl_xor(v, 16);
            v += __shfl_xor(v, 32);
            if (lane < 16) atomicAdd(&msum[colg[ct]], v);
          }
        }
        __syncthreads();   // B3: m16/msum final

        // U = tabU gather + M@Wu_m
        floatx4 au[2][4];
        #pragma unroll
        for (int rt = 0; rt < 2; ++rt)
          #pragma unroll
          for (int ct = 0; ct < 4; ++ct) {
            au[rt][ct] = (floatx4){0.f,0.f,0.f,0.f};
            if (rt < nvt) {
              #pragma unroll
              for (int r = 0; r < 4; ++r) {
                int lrow = rh2*32 + rt*16 + q*4 + r;
                au[rt][ct][r] = tabU[id_s[lrow]*128 + colg[ct]];
              }
            }
          }
        MFMA_HALF(m_a, wum, au, 0)
        MFMA_HALF(m_a, wum, au, 2)
        __syncthreads();   // B4: done reading m_a

        #pragma unroll
        for (int rt = 0; rt < 2; ++rt)
          if (rt < nvt) {
            #pragma unroll
            for (int ct = 0; ct < 4; ++ct) {
              float buv = bu[colg[ct]];
              #pragma unroll
              for (int r = 0; r < 4; ++r) {
                int lrow = rh2*32 + rt*16 + q*4 + r;
                m16[lrow*136 + colg[ct]] = bf16_1(fmaxf(au[rt][ct][r] + buv, 0.f));
              }
            }
          }
        __syncthreads();   // B5: m16 final
        #pragma unroll
        for (int it = 0; it < 4; ++it) {
          int f = it*256 + t;
          int lr = f >> 4, c4 = (f & 15) * 4;
          if (row0 + lr < vn)
            *(uint4*)&eblk[(size_t)(row0 + lr)*64 + c4] = *(const uint4*)&m_a[lr*68 + c4];
        }
      }
      if (t < 128) ms[(size_t)(b*128 + j)*128 + t] = msum[t];   // exclusive owner
    }
    if (t == 0) task_s = (int)atomicAdd(qc, 1u);
    __syncthreads();
    chunk = task_s;
    __syncthreads();
  }
}

// ---------- edge rounds >=1: persistent blocks, LDS-staged E, lean body ----------
__global__ __launch_bounds__(256,4) void edge_round_rest(
  unsigned* __restrict__ eg,
  const unsigned* __restrict__ wT,
  const float* __restrict__ a_l, const float* __restrict__ b_l,
  const float* __restrict__ a_m, const float* __restrict__ b_m,
  const float* __restrict__ bl1, const float* __restrict__ wl2,
  const float* __restrict__ bl2, const float* __restrict__ bm,
  const float* __restrict__ bu,
  const int* __restrict__ event_nums,
  float* __restrict__ ms, unsigned* __restrict__ qc)
{
  __shared__ unsigned e_s[64*68];
  __shared__ unsigned m_a[64*68];
  __shared__ float adj[64], msum[128];
  __shared__ int task_s;
  unsigned short* m16 = (unsigned short*)m_a;

  const int t = threadIdx.x;
  const int lane = t & 63, wv = t >> 6;
  const int q = lane >> 4, n = lane & 15;
  const int rh2 = wv >> 1, ch = wv & 1;
  int colg[4];
  #pragma unroll
  for (int ct = 0; ct < 4; ++ct) colg[ct] = ch*64 + ct*16 + n;
  int arowi[2];
  #pragma unroll
  for (int rt = 0; rt < 2; ++rt) arowi[rt] = rh2*32 + rt*16 + n;

  const unsigned* wz  = wT;
  const unsigned* wm  = wT + 8192;
  const unsigned* wue = wT + 16384;
  const unsigned* wum = wT + 24576;
  const float bl2v = bl2[0];

  int chunk = blockIdx.x;
  while (chunk < NCHUNK) {
    const int b = chunk >> 7, j = chunk & 127;
    const int vn = event_nums[b];
    if (j < vn) {
      unsigned* eblk = eg + (size_t)(b*128 + j) * 8192;
      if (t < 128) msum[t] = 0.f;
      const int nhalf = (vn > 64) ? 2 : 1;
      for (int hh = 0; hh < nhalf; ++hh) {
        const int row0 = hh*64;
        int vnl = vn - row0; if (vnl > 64) vnl = 64;
        int nvt = (vnl - rh2*32 + 15) >> 4;
        nvt = nvt < 0 ? 0 : (nvt > 2 ? 2 : nvt);

        if (t < 64) adj[t] = 0.f;
        // stage E tile -> LDS (coalesced 16B per thread)
        {
          const int vnc16 = (vnl + 15) & ~15;
          const int srow = t >> 4, c4 = (t & 15) * 4;
          #pragma unroll
          for (int it = 0; it < 4; ++it) {
            int lr = it*16 + srow;
            if (lr < vnc16)
              *(uint4*)&e_s[lr*68 + c4] = *(const uint4*)&eblk[(size_t)(row0 + lr)*64 + c4];
          }
        }
        __syncthreads();   // B1: e_s staged, adj zero

        // ---------- PASS Z ----------
        floatx4 az[2][4];
        #pragma unroll
        for (int rt = 0; rt < 2; ++rt)
          #pragma unroll
          for (int ct = 0; ct < 4; ++ct) az[rt][ct] = (floatx4){0.f,0.f,0.f,0.f};
        MFMA_HALF(e_s, wz, az, 0)
        MFMA_HALF(e_s, wz, az, 2)

        // Z epilogue (a_l inline)
        {
          float wl2v[4], bLv[4];
          #pragma unroll
          for (int ct = 0; ct < 4; ++ct) {
            int c = colg[ct];
            wl2v[ct] = wl2[c];
            bLv[ct]  = b_l[(size_t)(b*128 + j)*128 + c] + bl1[c];
          }
          const float* aLb = a_l + (size_t)(b*128 + row0)*128;
          #pragma unroll
          for (int rt = 0; rt < 2; ++rt) {
            if (rt < nvt) {
              float szr[4] = {0.f,0.f,0.f,0.f};
              #pragma unroll
              for (int ct = 0; ct < 4; ++ct) {
                #pragma unroll
                for (int r = 0; r < 4; ++r) {
                  int lrow = rh2*32 + rt*16 + q*4 + r;
                  float zv = fmaxf(az[rt][ct][r]
                                   + aLb[(size_t)lrow*128 + colg[ct]] + bLv[ct], 0.f);
                  szr[r] += zv * wl2v[ct];
                }
              }
              #pragma unroll
              for (int r = 0; r < 4; ++r) {
                szr[r] += __shfl_xor(szr[r], 1);
                szr[r] += __shfl_xor(szr[r], 2);
                szr[r] += __shfl_xor(szr[r], 4);
                szr[r] += __shfl_xor(szr[r], 8);
              }
              if (n == 0) {
                #pragma unroll
                for (int r = 0; r < 4; ++r)
                  atomicAdd(&adj[rh2*32 + rt*16 + q*4 + r], szr[r]);
              }
            }
          }
        }
        __syncthreads();   // B2: adj final

        // ---------- PASS M ----------
        floatx4 am[2][4];
        #pragma unroll
        for (int rt = 0; rt < 2; ++rt)
          #pragma unroll
          for (int ct = 0; ct < 4; ++ct) am[rt][ct] = (floatx4){0.f,0.f,0.f,0.f};
        MFMA_HALF(e_s, wm, am, 0)
        MFMA_HALF(e_s, wm, am, 2)

        // M epilogue (a_m inline, per-thread sigmoid)
        {
          float bMv[4];
          #pragma unroll
          for (int ct = 0; ct < 4; ++ct) {
            int c = colg[ct];
            bMv[ct] = b_m[(size_t)(b*128 + j)*128 + c] + bm[c];
          }
          const float* aMb = a_m + (size_t)(b*128 + row0)*128;
          float colsum[4] = {0.f,0.f,0.f,0.f};
          #pragma unroll
          for (int rt = 0; rt < 2; ++rt) {
            if (rt < nvt) {
              #pragma unroll
              for (int r = 0; r < 4; ++r) {
                int lrow = rh2*32 + rt*16 + q*4 + r;
                float sc = (lrow < vnl) ? sigf(adj[lrow] + bl2v) : 0.f;
                #pragma unroll
                for (int ct = 0; ct < 4; ++ct) {
                  float mv = fmaxf(am[rt][ct][r]
                                   + aMb[(size_t)lrow*128 + colg[ct]] + bMv[ct], 0.f) * sc;
                  m16[lrow*136 + colg[ct]] = bf16_1(mv);
                  colsum[ct] += mv;
                }
              }
            }
          }
          #pragma unroll
          for (int ct = 0; ct < 4; ++ct) {
            float v = colsum[ct];
            v += __shfl_xor(v, 16);
            v += __shfl_xor(v, 32);
            if (lane < 16) atomicAdd(&msum[colg[ct]], v);
          }
        }
        __syncthreads();   // B3: m16/msum final

        // ---------- PASS U ----------
        floatx4 au[2][4];
        #pragma unroll
        for (int rt = 0; rt < 2; ++rt)
          #pragma unroll
          for (int ct = 0; ct < 4; ++ct) au[rt][ct] = (floatx4){0.f,0.f,0.f,0.f};
        MFMA_HALF(e_s, wue, au, 0)
        MFMA_HALF(e_s, wue, au, 2)
        MFMA_HALF(m_a, wum, au, 0)
        MFMA_HALF(m_a, wum, au, 2)
        __syncthreads();   // B4: done reading m_a & e_s

        #pragma unroll
        for (int rt = 0; rt < 2; ++rt)
          if (rt < nvt) {
            #pragma unroll
            for (int ct = 0; ct < 4; ++ct) {
              float buv = bu[colg[ct]];
              #pragma unroll
              for (int r = 0; r < 4; ++r) {
                int lrow = rh2*32 + rt*16 + q*4 + r;
                m16[lrow*136 + colg[ct]] = bf16_1(fmaxf(au[rt][ct][r] + buv, 0.f));
              }
            }
          }
        __syncthreads();   // B5: m16 final
        #pragma unroll
        for (int it = 0; it < 4; ++it) {
          int f = it*256 + t;
          int lr = f >> 4, c4 = (f & 15) * 4;
          if (row0 + lr < vn)
            *(uint4*)&eblk[(size_t)(row0 + lr)*64 + c4] = *(const uint4*)&m_a[lr*68 + c4];
        }
      }
      if (t < 128) ms[(size_t)(b*128 + j)*128 + t] = msum[t];   // exclusive owner
    }
    if (t == 0) task_s = (int)atomicAdd(qc, 1u);
    __syncthreads();
    chunk = task_s;
    __syncthreads();
  }
}

// ---------- MFMA readout, both GEMMs on matrix cores ----------
__global__ __launch_bounds__(256,4) void readout_mfma(
  const unsigned* __restrict__ eg,
  const unsigned* __restrict__ wr1T,
  const unsigned* __restrict__ wr2T,
  const float* __restrict__ br1, const float* __restrict__ br2,
  const int* __restrict__ event_nums, float* __restrict__ out)
{
  __shared__ unsigned f_s[64*132];
  __shared__ int iu_s[64], ju_s[64];
  unsigned short* h16 = (unsigned short*)f_s;

  const int t = threadIdx.x;
  const int b = blockIdx.x / 127, pb = blockIdx.x % 127;
  const int vn = event_nums[b];

  if (t < 64) {
    int p = pb*64 + t;
    float disc = (float)((2*NN-1)*(2*NN-1) - 8*p);
    int iu = (int)(((float)(2*NN-1) - sqrtf(disc)) * 0.5f);
    if (iu < 0) iu = 0; if (iu > NN-2) iu = NN-2;
    while (iu < NN-2 && ((iu+1)*(2*NN-2-iu))/2 <= p) ++iu;
    while (iu > 0 && (iu*(2*NN-1-iu))/2 > p) --iu;
    int ju = p - (iu*(2*NN-1-iu))/2 + iu + 1;
    iu_s[t] = iu; ju_s[t] = ju;
  }
  __syncthreads();

  #pragma unroll
  for (int it = 0; it < 8; ++it) {
    int f4 = it*1024 + t*4;
    int pr = f4 >> 7, w = f4 & 127;
    int side = w >> 6, k2 = w & 63;
    int iu = iu_s[pr], ju = ju_s[pr];
    size_t base = side ? (((size_t)(b*128 + iu))*128 + ju)*64
                       : (((size_t)(b*128 + ju))*128 + iu)*64;
    *(uint4*)&f_s[pr*132 + w] = *(const uint4*)&eg[base + k2];
  }
  __syncthreads();

  const int lane = t & 63, wv = t >> 6;
  const int q = lane >> 4, n = lane & 15;
  int colg[4];
  #pragma unroll
  for (int ct = 0; ct < 4; ++ct) colg[ct] = wv*64 + ct*16 + n;

  floatx4 acc[4][4];
  #pragma unroll
  for (int rt = 0; rt < 4; ++rt)
    #pragma unroll
    for (int ct = 0; ct < 4; ++ct) acc[rt][ct] = (floatx4){0.f,0.f,0.f,0.f};

  #pragma unroll
  for (int kb = 0; kb < 8; ++kb) {
    uint4 bb[4];
    #pragma unroll
    for (int ct = 0; ct < 4; ++ct) bb[ct] = *(const uint4*)(wr1T + (size_t)colg[ct]*128 + kb*16 + q*4);
    #pragma unroll
    for (int rt = 0; rt < 4; ++rt) {
      uint4 a = *(const uint4*)&f_s[(rt*16 + n)*132 + kb*16 + q*4];
      #pragma unroll
      for (int ct = 0; ct < 4; ++ct)
        acc[rt][ct] = __builtin_amdgcn_mfma_f32_16x16x32_bf16(as_s8(a), as_s8(bb[ct]), acc[rt][ct], 0, 0, 0);
    }
  }
  __syncthreads();

  {
    float brv[4];
    #pragma unroll
    for (int ct = 0; ct < 4; ++ct) brv[ct] = br1[colg[ct]];
    #pragma unroll
    for (int rt = 0; rt < 4; ++rt)
      #pragma unroll
      for (int ct = 0; ct < 4; ++ct)
        #pragma unroll
        for (int r = 0; r < 4; ++r) {
          int pr = rt*16 + q*4 + r;
          h16[pr*264 + colg[ct]] = bf16_1(fmaxf(acc[rt][ct][r] + brv[ct], 0.f));
        }
  }
  __syncthreads();

  floatx4 acc2 = (floatx4){0.f,0.f,0.f,0.f};
  #pragma unroll
  for (int kb = 0; kb < 8; ++kb) {
    uint4 bb = *(const uint4*)(wr2T + n*128 + kb*16 + q*4);
    uint4 a  = *(const uint4*)&f_s[(wv*16 + n)*132 + kb*16 + q*4];
    acc2 = __builtin_amdgcn_mfma_f32_16x16x32_bf16(as_s8(a), as_s8(bb), acc2, 0, 0, 0);
  }

  if (n < 10) {
    float bias = br2[n];
    #pragma unroll
    for (int r = 0; r < 4; ++r) {
      int pr = wv*16 + q*4 + r;
      int iu = iu_s[pr], ju = ju_s[pr];
      if (ju < vn) {
        int idx = iu*vn - (iu*(iu+1))/2 + (ju - iu - 1);
        out[(((size_t)b*5 + (n>>1))*PP + idx)*2 + (n&1)] = acc2[r] + bias;
      }
    }
  }
}

extern "C" void kernel_launch(void* const* d_in, const int* in_sizes, int n_in,
                              void* d_out, int out_size, void* d_ws, size_t ws_size,
                              hipStream_t stream) {
  const int*   edge_ids      = (const int*)d_in[0];
  const float* node_features = (const float*)d_in[1];
  const int*   event_nums    = (const int*)d_in[3];
  const float* emb  = (const float*)d_in[4];
  const float* Wl_e = (const float*)d_in[5];
  const float* Wl_w = (const float*)d_in[6];
  const float* Wl_v = (const float*)d_in[7];
  const float* bl1  = (const float*)d_in[8];
  const float* wl2  = (const float*)d_in[9];
  const float* bl2  = (const float*)d_in[10];
  const float* Wm_w = (const float*)d_in[11];
  const float* Wm_v = (const float*)d_in[12];
  const float* Wm_e = (const float*)d_in[13];
  const float* bm   = (const float*)d_in[14];
  const float* Wu_e = (const float*)d_in[15];
  const float* Wu_m = (const float*)d_in[16];
  const float* bu   = (const float*)d_in[17];
  const float* W_ih = (const float*)d_in[18];
  const float* W_hh = (const float*)d_in[19];
  const float* b_ih = (const float*)d_in[20];
  const float* b_hh = (const float*)d_in[21];
  const float* Wr1  = (const float*)d_in[22];
  const float* br1  = (const float*)d_in[23];
  const float* Wr2  = (const float*)d_in[24];
  const float* br2  = (const float*)d_in[25];

  const size_t SZ_E = (size_t)134217728;       // B*N*N*64 u32
  const size_t SZ_S = (size_t)2097152;         // B*N*128 f32
  const size_t SZ_W = (size_t)131072;          // 32768 u32
  const size_t SZ_W2 = (size_t)8192;           // 2048 u32
  const size_t SZ_TAB = (size_t)2048;          // 512 f32 each
  const size_t SZ_Q = (size_t)64;              // 16 u32 task counters
  const size_t need = SZ_E + 6*SZ_S + 2*SZ_W + SZ_W2 + 3*SZ_TAB + SZ_Q;

  hipMemsetAsync(d_out, 0, (size_t)out_size * sizeof(float), stream);
  if (ws_size < need) return;

  char* w = (char*)d_ws;
  unsigned* eg   = (unsigned*)w; w += SZ_E;
  float* h_ws = (float*)w; w += SZ_S;
  float* a_l  = (float*)w; w += SZ_S;
  float* b_l  = (float*)w; w += SZ_S;
  float* a_m  = (float*)w; w += SZ_S;
  float* b_m  = (float*)w; w += SZ_S;
  float* ms   = (float*)w; w += SZ_S;
  unsigned* wT   = (unsigned*)w; w += SZ_W;
  unsigned* wr1T = (unsigned*)w; w += SZ_W;
  unsigned* wr2T = (unsigned*)w; w += SZ_W2;
  float* embZ = (float*)w; w += SZ_TAB;
  float* embM = (float*)w; w += SZ_TAB;
  float* embU = (float*)w; w += SZ_TAB;
  unsigned* qctr = (unsigned*)w; w += SZ_Q;

  hipLaunchKernelGGL(conv_w_kernel, dim3(256), dim3(256), 0, stream,
      Wl_e, Wm_e, Wu_e, Wu_m, Wr1, Wr2, emb, wT, wr1T, wr2T, embZ, embM, embU, qctr);

  hipLaunchKernelGGL(gru_proj_kernel, dim3(1024), dim3(256), 0, stream,
      0, ms, node_features, h_ws, W_ih, W_hh, b_ih, b_hh,
      Wl_w, Wl_v, Wm_w, Wm_v, event_nums, a_l, b_l, a_m, b_m);

  for (int r = 0; r < 3; ++r) {
    if (r == 0) {
      hipLaunchKernelGGL(edge_round_first, dim3(QGRID), dim3(256), 0, stream,
          eg, wT, edge_ids, embZ, embM, embU,
          a_l, b_l, a_m, b_m, bl1, wl2, bl2, bm, bu, event_nums, ms, qctr + 0);
    } else {
      hipLaunchKernelGGL(edge_round_rest, dim3(QGRID), dim3(256), 0, stream,
          eg, wT, a_l, b_l, a_m, b_m, bl1, wl2, bl2, bm, bu, event_nums, ms, qctr + r);
    }
    if (r < 2) {
      const float* hin = (r == 0) ? node_features : h_ws;
      hipLaunchKernelGGL(gru_proj_kernel, dim3(1024), dim3(256), 0, stream,
          1, ms, hin, h_ws, W_ih, W_hh, b_ih, b_hh,
          Wl_w, Wl_v, Wm_w, Wm_v, event_nums, a_l, b_l, a_m, b_m);
    }
  }

  hipLaunchKernelGGL(readout_mfma, dim3(BB*127), dim3(256), 0, stream,
      eg, wr1T, wr2T, br1, br2, event_nums, (float*)d_out);
}

// Round 5
// 759.486 us; speedup vs baseline: 3.1709x; 2.4343x over previous
//
#include <hip/hip_runtime.h>
#include <cstddef>

// Problem constants
#define BB 32
#define NN 128
#define PP 8128

typedef __attribute__((ext_vector_type(8))) short short8;
typedef __attribute__((ext_vector_type(4))) float floatx4;

union U4S8 { uint4 u; short8 s; };
__device__ __forceinline__ short8 as_s8(uint4 v){ U4S8 x; x.u = v; return x.s; }

// ---------- bf16 helpers ----------
__device__ __forceinline__ unsigned pack_bf16(float a, float b){
  union{float f;unsigned u;}xa,xb; xa.f=a; xb.f=b;
  unsigned ua=xa.u, ub=xb.u;
  ua = (ua + 0x7fffu + ((ua>>16)&1u)) >> 16;
  ub = (ub + 0x7fffu + ((ub>>16)&1u)) >> 16;
  return (ua & 0xffffu) | (ub << 16);
}
__device__ __forceinline__ unsigned short bf16_1(float a){
  union{float f;unsigned u;}x; x.f=a;
  return (unsigned short)((x.u + 0x7fffu + ((x.u>>16)&1u)) >> 16);
}
__device__ __forceinline__ float sigf(float x){ return 1.f/(1.f + __expf(-x)); }

// Bijective block remap. CU residue class = gid mod 256 (varying bits are 12..8).
// b <- {12,11 | 7,6,5}, j <- {10,9 | 4..0}, half <- {8}: every residue class spans
// 4 b's x 4 j-strata x 2 halves -> no pinned dimension (R1 pinned half; 3:1 skew).
__device__ __forceinline__ void decode_blk(int gid, int& b, int& j, int& half){
  b    = ((gid>>11)&3)*8 + ((gid>>5)&7);
  j    = ((gid>>9)&3)*32 + (gid&31);
  half = (gid>>8)&1;
}

// ---------- weight conversion + round-0 tables ----------
__global__ __launch_bounds__(256,4) void conv_w_kernel(
  const float* __restrict__ Wl_e, const float* __restrict__ Wm_e,
  const float* __restrict__ Wu_e, const float* __restrict__ Wu_m,
  const float* __restrict__ Wr1, const float* __restrict__ Wr2,
  const float* __restrict__ emb,
  unsigned* __restrict__ wT, unsigned* __restrict__ wr1T,
  unsigned* __restrict__ wr2T,
  float* __restrict__ embZ, float* __restrict__ embM, float* __restrict__ embU)
{
  int tid = blockIdx.x*256 + threadIdx.x;   // 65536 total
  if (tid < 2048) {   // Wr2 [256][10] -> B-frag layout [16 cols][128 k2], zero-padded
    int c = tid >> 7, k2 = tid & 127;
    unsigned v = 0;
    if (c < 10) v = pack_bf16(Wr2[(2*k2)*10 + c], Wr2[(2*k2+1)*10 + c]);
    wr2T[c*128 + k2] = v;
  }
  if (tid >= 4096 && tid < 5632) {   // round-0 tables: emb(4x128) @ W(128x128), f32
    int idx = tid - 4096;            // 0..1535
    int tb = idx >> 9;               // 0..2
    int r  = idx & 511;
    int id = r >> 7, c = r & 127;
    const float* W = (tb==0) ? Wl_e : (tb==1) ? Wm_e : Wu_e;
    float s = 0.f;
    #pragma unroll 4
    for (int k = 0; k < 128; ++k) s += emb[id*128 + k] * W[(size_t)k*128 + c];
    float* T = (tb==0) ? embZ : (tb==1) ? embM : embU;
    T[r] = s;
  }
  if (tid < 32768) {
    int mat = tid >> 13, r = tid & 8191;
    int k2 = r >> 7, c = r & 127;
    const float* W = (mat==0) ? Wl_e : (mat==1) ? Wm_e : (mat==2) ? Wu_e : Wu_m;
    wT[mat*8192 + c*64 + k2] = pack_bf16(W[(2*k2)*128 + c], W[(2*k2+1)*128 + c]);
  } else {
    int r = tid - 32768;
    int k2 = r >> 8, c = r & 255;
    wr1T[(size_t)c*128 + k2] = pack_bf16(Wr1[(2*k2)*256 + c], Wr1[(2*k2+1)*256 + c]);
  }
}

// ---------- fused GRU + node projections ----------
__global__ __launch_bounds__(256,4) void gru_proj_kernel(
  int do_gru,
  const float* __restrict__ ms0, const float* __restrict__ ms1,
  const float* __restrict__ h_in, float* __restrict__ h_out,
  const float* __restrict__ W_ih, const float* __restrict__ W_hh,
  const float* __restrict__ b_ih, const float* __restrict__ b_hh,
  const float* __restrict__ Wl_w, const float* __restrict__ Wl_v,
  const float* __restrict__ Wm_w, const float* __restrict__ Wm_v,
  const int* __restrict__ event_nums,
  float* __restrict__ a_l, float* __restrict__ b_l,
  float* __restrict__ a_m, float* __restrict__ b_m)
{
  __shared__ float h_s[4][128];
  __shared__ float ms_s[4][128];
  const int t = threadIdx.x, blk = blockIdx.x;
  const int b = blk >> 5, n0 = (blk & 31) * 4;
  const int vn = event_nums[b];
  const int g = t >> 6, l = t & 63;
  const int row = b*128 + n0 + g;

  h_s[g][l]    = h_in[(size_t)row*128 + l];
  h_s[g][l+64] = h_in[(size_t)row*128 + l + 64];
  if (do_gru) {
    float v0 = ms0[(size_t)row*128 + l];
    float v1 = ms0[(size_t)row*128 + l + 64];
    if (vn > 64) {
      v0 += ms1[(size_t)row*128 + l];
      v1 += ms1[(size_t)row*128 + l + 64];
    }
    ms_s[g][l]    = v0;
    ms_s[g][l+64] = v1;
  }
  __syncthreads();

  if (do_gru) {
    float acc[12] = {};
    #pragma unroll 4
    for (int k = 0; k < 128; ++k) {
      float mv = ms_s[g][k], hv = h_s[g][k];
      #pragma unroll
      for (int u = 0; u < 6; ++u) {
        acc[u]   += mv * W_ih[(size_t)k*384 + l + 64*u];
        acc[6+u] += hv * W_hh[(size_t)k*384 + l + 64*u];
      }
    }
    const bool valid = (n0 + g) < vn;
    float hnew[2];
    #pragma unroll
    for (int u = 0; u < 2; ++u) {
      int c = l + 64*u;
      float ir = acc[u]     + b_ih[c];
      float iz = acc[u+2]   + b_ih[128+c];
      float in_= acc[u+4]   + b_ih[256+c];
      float hr = acc[6+u]   + b_hh[c];
      float hz = acc[8+u]   + b_hh[128+c];
      float hn = acc[10+u]  + b_hh[256+c];
      float r  = sigf(ir + hr);
      float zg = sigf(iz + hz);
      float nn = tanhf(in_ + r*hn);
      float hold = h_s[g][c];
      hnew[u] = valid ? (1.f - zg)*nn + zg*hold : hold;
    }
    __syncthreads();
    #pragma unroll
    for (int u = 0; u < 2; ++u) {
      int c = l + 64*u;
      h_s[g][c] = hnew[u];
      h_out[(size_t)row*128 + c] = hnew[u];
    }
    __syncthreads();
  }

  {
    const float* Wp[4] = {Wl_w, Wl_v, Wm_w, Wm_v};
    float* Op[4] = {a_l, b_l, a_m, b_m};
    float acc2[8] = {};
    #pragma unroll 4
    for (int k = 0; k < 128; ++k) {
      float hv = h_s[g][k];
      #pragma unroll
      for (int u = 0; u < 8; ++u)
        acc2[u] += hv * Wp[u>>1][(size_t)k*128 + l + 64*(u&1)];
    }
    #pragma unroll
    for (int u = 0; u < 8; ++u)
      Op[u>>1][(size_t)row*128 + l + 64*(u&1)] = acc2[u];
  }
}

// ---------- edge round 0: table-driven (no E GEMMs), only M@Wu_m on MFMA ----------
__global__ __launch_bounds__(256,4) void edge_round_first(
  unsigned* __restrict__ eg,
  const unsigned* __restrict__ wT,     // need wum = wT+24576
  const int* __restrict__ ids,
  const float* __restrict__ embZ, const float* __restrict__ embM,
  const float* __restrict__ embU,
  const float* __restrict__ a_l, const float* __restrict__ b_l,
  const float* __restrict__ a_m, const float* __restrict__ b_m,
  const float* __restrict__ bl1, const float* __restrict__ wl2,
  const float* __restrict__ bl2, const float* __restrict__ bm,
  const float* __restrict__ bu,
  const int* __restrict__ event_nums,
  float* __restrict__ ms0, float* __restrict__ ms1)
{
  __shared__ unsigned m_a[64*68];
  __shared__ float adj[64], msum[128];
  __shared__ float bL_s[128], bM_s[128], bu_s[128], wl2_s[128];
  __shared__ float tabZ[512], tabM[512], tabU[512];
  __shared__ int id_s[64];
  unsigned short* m16 = (unsigned short*)m_a;

  const int t = threadIdx.x;
  int b, j, half;
  decode_blk(blockIdx.x, b, j, half);
  const int vn = event_nums[b];
  const int row0 = half*64;
  int vnl = vn - row0; vnl = vnl < 0 ? 0 : (vnl > 64 ? 64 : vnl);
  if (j >= vn || vnl == 0) return;

  unsigned* eblk = eg + (size_t)(b*128 + j) * 8192;
  const float bl2v = bl2[0];

  if (t < 128) {
    bL_s[t] = b_l[(size_t)(b*128 + j)*128 + t] + bl1[t];
    bM_s[t] = b_m[(size_t)(b*128 + j)*128 + t] + bm[t];
    bu_s[t] = bu[t];
    wl2_s[t] = wl2[t];
    msum[t] = 0.f;
  }
  if (t < 64) {
    adj[t] = 0.f;
    id_s[t] = ids[((size_t)(b*128 + row0 + t))*128 + j];
  }
  for (int i = t; i < 512; i += 256) {
    tabZ[i] = embZ[i]; tabM[i] = embM[i]; tabU[i] = embU[i];
  }

  const int lane = t & 63, wv = t >> 6;
  const int q = lane >> 4, n = lane & 15;
  const int rh2 = wv >> 1, ch = wv & 1;

  int nvt = (vnl - rh2*32 + 15) >> 4;
  nvt = nvt < 0 ? 0 : (nvt > 2 ? 2 : nvt);

  const unsigned* wum = wT + 24576;
  int colg[4];
  #pragma unroll
  for (int ct = 0; ct < 4; ++ct) colg[ct] = ch*64 + ct*16 + n;
  int arowi[2];
  #pragma unroll
  for (int rt = 0; rt < 2; ++rt) arowi[rt] = rh2*32 + rt*16 + n;

  // Prefetch a_l / a_m into registers (hide L2/L3 latency under barrier + tables)
  const float* aLb = a_l + (size_t)(b*128 + row0)*128;
  const float* aMb = a_m + (size_t)(b*128 + row0)*128;
  float alv[2][4][4], amv[2][4][4];
  #pragma unroll
  for (int rt = 0; rt < 2; ++rt)
    if (rt < nvt)
      #pragma unroll
      for (int ct = 0; ct < 4; ++ct)
        #pragma unroll
        for (int r = 0; r < 4; ++r) {
          int lrow = rh2*32 + rt*16 + q*4 + r;
          alv[rt][ct][r] = aLb[(size_t)lrow*128 + colg[ct]];
          amv[rt][ct][r] = aMb[(size_t)lrow*128 + colg[ct]];
        }
  __syncthreads();   // B1

  // Z epilogue from tables
  {
    float wl2v[4], bLv[4];
    #pragma unroll
    for (int ct = 0; ct < 4; ++ct) { wl2v[ct] = wl2_s[colg[ct]]; bLv[ct] = bL_s[colg[ct]]; }
    #pragma unroll
    for (int rt = 0; rt < 2; ++rt) {
      if (rt < nvt) {
        float szr[4] = {0.f,0.f,0.f,0.f};
        #pragma unroll
        for (int ct = 0; ct < 4; ++ct) {
          #pragma unroll
          for (int r = 0; r < 4; ++r) {
            int lrow = rh2*32 + rt*16 + q*4 + r;
            float zv = fmaxf(tabZ[id_s[lrow]*128 + colg[ct]] + alv[rt][ct][r] + bLv[ct], 0.f);
            szr[r] += zv * wl2v[ct];
          }
        }
        #pragma unroll
        for (int r = 0; r < 4; ++r) {
          szr[r] += __shfl_xor(szr[r], 1);
          szr[r] += __shfl_xor(szr[r], 2);
          szr[r] += __shfl_xor(szr[r], 4);
          szr[r] += __shfl_xor(szr[r], 8);
        }
        if (n == 0) {
          #pragma unroll
          for (int r = 0; r < 4; ++r)
            atomicAdd(&adj[rh2*32 + rt*16 + q*4 + r], szr[r]);
        }
      }
    }
  }
  __syncthreads();   // B2: adj final

  // M epilogue from tables -> m16, msum (per-thread sigmoid, no svec)
  {
    float bMv[4];
    #pragma unroll
    for (int ct = 0; ct < 4; ++ct) bMv[ct] = bM_s[colg[ct]];
    float colsum[4] = {0.f,0.f,0.f,0.f};
    #pragma unroll
    for (int rt = 0; rt < 2; ++rt) {
      if (rt < nvt) {
        #pragma unroll
        for (int r = 0; r < 4; ++r) {
          int lrow = rh2*32 + rt*16 + q*4 + r;
          float sc = (lrow < vnl) ? sigf(adj[lrow] + bl2v) : 0.f;
          #pragma unroll
          for (int ct = 0; ct < 4; ++ct) {
            float mv = fmaxf(tabM[id_s[lrow]*128 + colg[ct]] + amv[rt][ct][r] + bMv[ct], 0.f) * sc;
            m16[lrow*136 + colg[ct]] = bf16_1(mv);
            colsum[ct] += mv;
          }
        }
      }
    }
    #pragma unroll
    for (int ct = 0; ct < 4; ++ct) {
      float v = colsum[ct];
      v += __shfl_xor(v, 16);
      v += __shfl_xor(v, 32);
      if (lane < 16) atomicAdd(&msum[colg[ct]], v);
    }
  }
  __syncthreads();   // B3
  {
    float* msH = half ? ms1 : ms0;
    if (t < 128) msH[(size_t)(b*128 + j)*128 + t] = msum[t];   // exclusive owner
  }

  // U = tabU gather + M@Wu_m
  floatx4 au[2][4];
  #pragma unroll
  for (int rt = 0; rt < 2; ++rt)
    #pragma unroll
    for (int ct = 0; ct < 4; ++ct) {
      au[rt][ct] = (floatx4){0.f,0.f,0.f,0.f};
      if (rt < nvt)
        #pragma unroll
        for (int r = 0; r < 4; ++r) {
          int lrow = rh2*32 + rt*16 + q*4 + r;
          au[rt][ct][r] = tabU[id_s[lrow]*128 + colg[ct]];
        }
    }
  #pragma unroll
  for (int kb = 0; kb < 4; ++kb) {
    uint4 bb[4];
    #pragma unroll
    for (int ct = 0; ct < 4; ++ct) bb[ct] = *(const uint4*)(wum + colg[ct]*64 + kb*16 + q*4);
    #pragma unroll
    for (int rt = 0; rt < 2; ++rt)
      if (rt < nvt) {
        uint4 a = *(const uint4*)&m_a[arowi[rt]*68 + kb*16 + q*4];
        #pragma unroll
        for (int ct = 0; ct < 4; ++ct)
          au[rt][ct] = __builtin_amdgcn_mfma_f32_16x16x32_bf16(as_s8(a), as_s8(bb[ct]), au[rt][ct], 0, 0, 0);
      }
  }
  __syncthreads();   // B4

  {
    float buv[4];
    #pragma unroll
    for (int ct = 0; ct < 4; ++ct) buv[ct] = bu_s[colg[ct]];
    #pragma unroll
    for (int rt = 0; rt < 2; ++rt)
      if (rt < nvt)
        #pragma unroll
        for (int ct = 0; ct < 4; ++ct)
          #pragma unroll
          for (int r = 0; r < 4; ++r) {
            int lrow = rh2*32 + rt*16 + q*4 + r;
            m16[lrow*136 + colg[ct]] = bf16_1(fmaxf(au[rt][ct][r] + buv[ct], 0.f));
          }
  }
  __syncthreads();   // B5
  #pragma unroll
  for (int it = 0; it < 4; ++it) {
    int f = it*256 + t;
    int lr = f >> 4, c4 = (f & 15) * 4;
    if (row0 + lr < vn)
      *(uint4*)&eblk[(size_t)(row0 + lr)*64 + c4] = *(const uint4*)&m_a[lr*68 + c4];
  }
}

// ---------- edge rounds >=1: 3 MFMA passes, LDS-staged E, 64-row half-blocks ----------
__global__ __launch_bounds__(256,4) void edge_round_rest(
  unsigned* __restrict__ eg,
  const unsigned* __restrict__ wT,
  const float* __restrict__ a_l, const float* __restrict__ b_l,
  const float* __restrict__ a_m, const float* __restrict__ b_m,
  const float* __restrict__ bl1, const float* __restrict__ wl2,
  const float* __restrict__ bl2, const float* __restrict__ bm,
  const float* __restrict__ bu,
  const int* __restrict__ event_nums,
  float* __restrict__ ms0, float* __restrict__ ms1)
{
  __shared__ unsigned e_s[64*68];
  __shared__ unsigned m_a[64*68];
  __shared__ float adj[64], msum[128];
  __shared__ float bL_s[128], bM_s[128], bu_s[128], wl2_s[128];
  unsigned short* m16 = (unsigned short*)m_a;

  const int t = threadIdx.x;
  int b, j, half;
  decode_blk(blockIdx.x, b, j, half);
  const int vn = event_nums[b];
  const int row0 = half*64;
  int vnl = vn - row0; vnl = vnl < 0 ? 0 : (vnl > 64 ? 64 : vnl);
  if (j >= vn || vnl == 0) return;

  unsigned* eblk = eg + (size_t)(b*128 + j) * 8192;
  const float bl2v = bl2[0];

  if (t < 128) {
    bL_s[t] = b_l[(size_t)(b*128 + j)*128 + t] + bl1[t];
    bM_s[t] = b_m[(size_t)(b*128 + j)*128 + t] + bm[t];
    bu_s[t] = bu[t];
    wl2_s[t] = wl2[t];
    msum[t] = 0.f;
  }
  if (t < 64) adj[t] = 0.f;
  {
    const int vnc16 = (vnl + 15) & ~15;
    const int srow = t >> 4, c4 = (t & 15) * 4;
    #pragma unroll
    for (int it = 0; it < 4; ++it) {
      int lr = it*16 + srow;
      if (lr < vnc16)
        *(uint4*)&e_s[lr*68 + c4] = *(const uint4*)&eblk[(size_t)(row0 + lr)*64 + c4];
    }
  }

  const int lane = t & 63, wv = t >> 6;
  const int q = lane >> 4, n = lane & 15;
  const int rh2 = wv >> 1, ch = wv & 1;

  int nvt = (vnl - rh2*32 + 15) >> 4;
  nvt = nvt < 0 ? 0 : (nvt > 2 ? 2 : nvt);

  const unsigned* wz  = wT;
  const unsigned* wm  = wT + 8192;
  const unsigned* wue = wT + 16384;
  const unsigned* wum = wT + 24576;

  int colg[4];
  #pragma unroll
  for (int ct = 0; ct < 4; ++ct) colg[ct] = ch*64 + ct*16 + n;
  int arowi[2];
  #pragma unroll
  for (int rt = 0; rt < 2; ++rt) arowi[rt] = rh2*32 + rt*16 + n;

  // Prefetch a_l into registers pre-B1: latency hides under staging + Z MFMA.
  const float* aLb = a_l + (size_t)(b*128 + row0)*128;
  const float* aMb = a_m + (size_t)(b*128 + row0)*128;
  float alv[2][4][4];
  #pragma unroll
  for (int rt = 0; rt < 2; ++rt)
    if (rt < nvt)
      #pragma unroll
      for (int ct = 0; ct < 4; ++ct)
        #pragma unroll
        for (int r = 0; r < 4; ++r) {
          int lrow = rh2*32 + rt*16 + q*4 + r;
          alv[rt][ct][r] = aLb[(size_t)lrow*128 + colg[ct]];
        }
  __syncthreads();   // B1

  // ---------- PASS Z ----------
  floatx4 az[2][4];
  #pragma unroll
  for (int rt = 0; rt < 2; ++rt)
    #pragma unroll
    for (int ct = 0; ct < 4; ++ct) az[rt][ct] = (floatx4){0.f,0.f,0.f,0.f};
  #pragma unroll
  for (int kp = 0; kp < 2; ++kp) {   // two kb per iteration: 8 B-loads in flight
    uint4 bb[2][4];
    #pragma unroll
    for (int k2 = 0; k2 < 2; ++k2)
      #pragma unroll
      for (int ct = 0; ct < 4; ++ct)
        bb[k2][ct] = *(const uint4*)(wz + colg[ct]*64 + (kp*2 + k2)*16 + q*4);
    #pragma unroll
    for (int k2 = 0; k2 < 2; ++k2)
      #pragma unroll
      for (int rt = 0; rt < 2; ++rt)
        if (rt < nvt) {
          uint4 a = *(const uint4*)&e_s[arowi[rt]*68 + (kp*2 + k2)*16 + q*4];
          #pragma unroll
          for (int ct = 0; ct < 4; ++ct)
            az[rt][ct] = __builtin_amdgcn_mfma_f32_16x16x32_bf16(as_s8(a), as_s8(bb[k2][ct]), az[rt][ct], 0, 0, 0);
        }
  }

  // Z epilogue (consume prefetched alv)
  {
    float wl2v[4], bLv[4];
    #pragma unroll
    for (int ct = 0; ct < 4; ++ct) { wl2v[ct] = wl2_s[colg[ct]]; bLv[ct] = bL_s[colg[ct]]; }
    #pragma unroll
    for (int rt = 0; rt < 2; ++rt) {
      if (rt < nvt) {
        float szr[4] = {0.f,0.f,0.f,0.f};
        #pragma unroll
        for (int ct = 0; ct < 4; ++ct) {
          #pragma unroll
          for (int r = 0; r < 4; ++r) {
            float zv = fmaxf(az[rt][ct][r] + alv[rt][ct][r] + bLv[ct], 0.f);
            szr[r] += zv * wl2v[ct];
          }
        }
        #pragma unroll
        for (int r = 0; r < 4; ++r) {
          szr[r] += __shfl_xor(szr[r], 1);
          szr[r] += __shfl_xor(szr[r], 2);
          szr[r] += __shfl_xor(szr[r], 4);
          szr[r] += __shfl_xor(szr[r], 8);
        }
        if (n == 0) {
          #pragma unroll
          for (int r = 0; r < 4; ++r)
            atomicAdd(&adj[rh2*32 + rt*16 + q*4 + r], szr[r]);
        }
      }
    }
  }

  // Prefetch a_m now (alv dead): latency hides under B2 + M MFMA.
  float amv[2][4][4];
  #pragma unroll
  for (int rt = 0; rt < 2; ++rt)
    if (rt < nvt)
      #pragma unroll
      for (int ct = 0; ct < 4; ++ct)
        #pragma unroll
        for (int r = 0; r < 4; ++r) {
          int lrow = rh2*32 + rt*16 + q*4 + r;
          amv[rt][ct][r] = aMb[(size_t)lrow*128 + colg[ct]];
        }
  __syncthreads();   // B2: adj final

  // ---------- PASS M ----------
  floatx4 am[2][4];
  #pragma unroll
  for (int rt = 0; rt < 2; ++rt)
    #pragma unroll
    for (int ct = 0; ct < 4; ++ct) am[rt][ct] = (floatx4){0.f,0.f,0.f,0.f};
  #pragma unroll
  for (int kp = 0; kp < 2; ++kp) {
    uint4 bb[2][4];
    #pragma unroll
    for (int k2 = 0; k2 < 2; ++k2)
      #pragma unroll
      for (int ct = 0; ct < 4; ++ct)
        bb[k2][ct] = *(const uint4*)(wm + colg[ct]*64 + (kp*2 + k2)*16 + q*4);
    #pragma unroll
    for (int k2 = 0; k2 < 2; ++k2)
      #pragma unroll
      for (int rt = 0; rt < 2; ++rt)
        if (rt < nvt) {
          uint4 a = *(const uint4*)&e_s[arowi[rt]*68 + (kp*2 + k2)*16 + q*4];
          #pragma unroll
          for (int ct = 0; ct < 4; ++ct)
            am[rt][ct] = __builtin_amdgcn_mfma_f32_16x16x32_bf16(as_s8(a), as_s8(bb[k2][ct]), am[rt][ct], 0, 0, 0);
        }
  }

  // M epilogue (consume prefetched amv; per-thread sigmoid)
  {
    float bMv[4];
    #pragma unroll
    for (int ct = 0; ct < 4; ++ct) bMv[ct] = bM_s[colg[ct]];
    float colsum[4] = {0.f,0.f,0.f,0.f};
    #pragma unroll
    for (int rt = 0; rt < 2; ++rt) {
      if (rt < nvt) {
        #pragma unroll
        for (int r = 0; r < 4; ++r) {
          int lrow = rh2*32 + rt*16 + q*4 + r;
          float sc = (lrow < vnl) ? sigf(adj[lrow] + bl2v) : 0.f;
          #pragma unroll
          for (int ct = 0; ct < 4; ++ct) {
            float mv = fmaxf(am[rt][ct][r] + amv[rt][ct][r] + bMv[ct], 0.f) * sc;
            m16[lrow*136 + colg[ct]] = bf16_1(mv);
            colsum[ct] += mv;
          }
        }
      }
    }
    #pragma unroll
    for (int ct = 0; ct < 4; ++ct) {
      float v = colsum[ct];
      v += __shfl_xor(v, 16);
      v += __shfl_xor(v, 32);
      if (lane < 16) atomicAdd(&msum[colg[ct]], v);
    }
  }
  __syncthreads();   // B3
  {
    float* msH = half ? ms1 : ms0;
    if (t < 128) msH[(size_t)(b*128 + j)*128 + t] = msum[t];   // exclusive owner
  }

  // ---------- PASS U ----------
  floatx4 au[2][4];
  #pragma unroll
  for (int rt = 0; rt < 2; ++rt)
    #pragma unroll
    for (int ct = 0; ct < 4; ++ct) au[rt][ct] = (floatx4){0.f,0.f,0.f,0.f};
  #pragma unroll
  for (int kp = 0; kp < 2; ++kp) {
    uint4 bb[2][4];
    #pragma unroll
    for (int k2 = 0; k2 < 2; ++k2)
      #pragma unroll
      for (int ct = 0; ct < 4; ++ct)
        bb[k2][ct] = *(const uint4*)(wue + colg[ct]*64 + (kp*2 + k2)*16 + q*4);
    #pragma unroll
    for (int k2 = 0; k2 < 2; ++k2)
      #pragma unroll
      for (int rt = 0; rt < 2; ++rt)
        if (rt < nvt) {
          uint4 a = *(const uint4*)&e_s[arowi[rt]*68 + (kp*2 + k2)*16 + q*4];
          #pragma unroll
          for (int ct = 0; ct < 4; ++ct)
            au[rt][ct] = __builtin_amdgcn_mfma_f32_16x16x32_bf16(as_s8(a), as_s8(bb[k2][ct]), au[rt][ct], 0, 0, 0);
        }
  }
  #pragma unroll
  for (int kp = 0; kp < 2; ++kp) {
    uint4 bb[2][4];
    #pragma unroll
    for (int k2 = 0; k2 < 2; ++k2)
      #pragma unroll
      for (int ct = 0; ct < 4; ++ct)
        bb[k2][ct] = *(const uint4*)(wum + colg[ct]*64 + (kp*2 + k2)*16 + q*4);
    #pragma unroll
    for (int k2 = 0; k2 < 2; ++k2)
      #pragma unroll
      for (int rt = 0; rt < 2; ++rt)
        if (rt < nvt) {
          uint4 a = *(const uint4*)&m_a[arowi[rt]*68 + (kp*2 + k2)*16 + q*4];
          #pragma unroll
          for (int ct = 0; ct < 4; ++ct)
            au[rt][ct] = __builtin_amdgcn_mfma_f32_16x16x32_bf16(as_s8(a), as_s8(bb[k2][ct]), au[rt][ct], 0, 0, 0);
        }
  }
  __syncthreads();   // B4

  {
    float buv[4];
    #pragma unroll
    for (int ct = 0; ct < 4; ++ct) buv[ct] = bu_s[colg[ct]];
    #pragma unroll
    for (int rt = 0; rt < 2; ++rt)
      if (rt < nvt)
        #pragma unroll
        for (int ct = 0; ct < 4; ++ct)
          #pragma unroll
          for (int r = 0; r < 4; ++r) {
            int lrow = rh2*32 + rt*16 + q*4 + r;
            m16[lrow*136 + colg[ct]] = bf16_1(fmaxf(au[rt][ct][r] + buv[ct], 0.f));
          }
  }
  __syncthreads();   // B5
  #pragma unroll
  for (int it = 0; it < 4; ++it) {
    int f = it*256 + t;
    int lr = f >> 4, c4 = (f & 15) * 4;
    if (row0 + lr < vn)
      *(uint4*)&eblk[(size_t)(row0 + lr)*64 + c4] = *(const uint4*)&m_a[lr*68 + c4];
  }
}

// ---------- MFMA readout, both GEMMs on matrix cores ----------
__global__ __launch_bounds__(256,4) void readout_mfma(
  const unsigned* __restrict__ eg,
  const unsigned* __restrict__ wr1T,
  const unsigned* __restrict__ wr2T,
  const float* __restrict__ br1, const float* __restrict__ br2,
  const int* __restrict__ event_nums, float* __restrict__ out)
{
  __shared__ unsigned f_s[64*132];
  __shared__ int iu_s[64], ju_s[64];
  unsigned short* h16 = (unsigned short*)f_s;

  const int t = threadIdx.x;
  const int b = blockIdx.x / 127, pb = blockIdx.x % 127;
  const int vn = event_nums[b];

  if (t < 64) {
    int p = pb*64 + t;
    float disc = (float)((2*NN-1)*(2*NN-1) - 8*p);
    int iu = (int)(((float)(2*NN-1) - sqrtf(disc)) * 0.5f);
    if (iu < 0) iu = 0; if (iu > NN-2) iu = NN-2;
    while (iu < NN-2 && ((iu+1)*(2*NN-2-iu))/2 <= p) ++iu;
    while (iu > 0 && (iu*(2*NN-1-iu))/2 > p) --iu;
    int ju = p - (iu*(2*NN-1-iu))/2 + iu + 1;
    iu_s[t] = iu; ju_s[t] = ju;
  }
  __syncthreads();

  #pragma unroll
  for (int it = 0; it < 8; ++it) {
    int f4 = it*1024 + t*4;
    int pr = f4 >> 7, w = f4 & 127;
    int side = w >> 6, k2 = w & 63;
    int iu = iu_s[pr], ju = ju_s[pr];
    size_t base = side ? (((size_t)(b*128 + iu))*128 + ju)*64
                       : (((size_t)(b*128 + ju))*128 + iu)*64;
    *(uint4*)&f_s[pr*132 + w] = *(const uint4*)&eg[base + k2];
  }
  __syncthreads();

  const int lane = t & 63, wv = t >> 6;
  const int q = lane >> 4, n = lane & 15;
  int colg[4];
  #pragma unroll
  for (int ct = 0; ct < 4; ++ct) colg[ct] = wv*64 + ct*16 + n;

  floatx4 acc[4][4];
  #pragma unroll
  for (int rt = 0; rt < 4; ++rt)
    #pragma unroll
    for (int ct = 0; ct < 4; ++ct) acc[rt][ct] = (floatx4){0.f,0.f,0.f,0.f};

  #pragma unroll
  for (int kb = 0; kb < 8; ++kb) {
    uint4 bb[4];
    #pragma unroll
    for (int ct = 0; ct < 4; ++ct) bb[ct] = *(const uint4*)(wr1T + (size_t)colg[ct]*128 + kb*16 + q*4);
    #pragma unroll
    for (int rt = 0; rt < 4; ++rt) {
      uint4 a = *(const uint4*)&f_s[(rt*16 + n)*132 + kb*16 + q*4];
      #pragma unroll
      for (int ct = 0; ct < 4; ++ct)
        acc[rt][ct] = __builtin_amdgcn_mfma_f32_16x16x32_bf16(as_s8(a), as_s8(bb[ct]), acc[rt][ct], 0, 0, 0);
    }
  }
  __syncthreads();

  {
    float brv[4];
    #pragma unroll
    for (int ct = 0; ct < 4; ++ct) brv[ct] = br1[colg[ct]];
    #pragma unroll
    for (int rt = 0; rt < 4; ++rt)
      #pragma unroll
      for (int ct = 0; ct < 4; ++ct)
        #pragma unroll
        for (int r = 0; r < 4; ++r) {
          int pr = rt*16 + q*4 + r;
          h16[pr*264 + colg[ct]] = bf16_1(fmaxf(acc[rt][ct][r] + brv[ct], 0.f));
        }
  }
  __syncthreads();

  floatx4 acc2 = (floatx4){0.f,0.f,0.f,0.f};
  #pragma unroll
  for (int kb = 0; kb < 8; ++kb) {
    uint4 bb = *(const uint4*)(wr2T + n*128 + kb*16 + q*4);
    uint4 a  = *(const uint4*)&f_s[(wv*16 + n)*132 + kb*16 + q*4];
    acc2 = __builtin_amdgcn_mfma_f32_16x16x32_bf16(as_s8(a), as_s8(bb), acc2, 0, 0, 0);
  }

  if (n < 10) {
    float bias = br2[n];
    #pragma unroll
    for (int r = 0; r < 4; ++r) {
      int pr = wv*16 + q*4 + r;
      int iu = iu_s[pr], ju = ju_s[pr];
      if (ju < vn) {
        int idx = iu*vn - (iu*(iu+1))/2 + (ju - iu - 1);
        out[(((size_t)b*5 + (n>>1))*PP + idx)*2 + (n&1)] = acc2[r] + bias;
      }
    }
  }
}

extern "C" void kernel_launch(void* const* d_in, const int* in_sizes, int n_in,
                              void* d_out, int out_size, void* d_ws, size_t ws_size,
                              hipStream_t stream) {
  const int*   edge_ids      = (const int*)d_in[0];
  const float* node_features = (const float*)d_in[1];
  const int*   event_nums    = (const int*)d_in[3];
  const float* emb  = (const float*)d_in[4];
  const float* Wl_e = (const float*)d_in[5];
  const float* Wl_w = (const float*)d_in[6];
  const float* Wl_v = (const float*)d_in[7];
  const float* bl1  = (const float*)d_in[8];
  const float* wl2  = (const float*)d_in[9];
  const float* bl2  = (const float*)d_in[10];
  const float* Wm_w = (const float*)d_in[11];
  const float* Wm_v = (const float*)d_in[12];
  const float* Wm_e = (const float*)d_in[13];
  const float* bm   = (const float*)d_in[14];
  const float* Wu_e = (const float*)d_in[15];
  const float* Wu_m = (const float*)d_in[16];
  const float* bu   = (const float*)d_in[17];
  const float* W_ih = (const float*)d_in[18];
  const float* W_hh = (const float*)d_in[19];
  const float* b_ih = (const float*)d_in[20];
  const float* b_hh = (const float*)d_in[21];
  const float* Wr1  = (const float*)d_in[22];
  const float* br1  = (const float*)d_in[23];
  const float* Wr2  = (const float*)d_in[24];
  const float* br2  = (const float*)d_in[25];

  const size_t SZ_E = (size_t)134217728;       // B*N*N*64 u32
  const size_t SZ_S = (size_t)2097152;         // B*N*128 f32
  const size_t SZ_W = (size_t)131072;          // 32768 u32
  const size_t SZ_W2 = (size_t)8192;           // 2048 u32
  const size_t SZ_TAB = (size_t)2048;          // 512 f32 each
  const size_t need = SZ_E + 7*SZ_S + 2*SZ_W + SZ_W2 + 3*SZ_TAB;

  hipMemsetAsync(d_out, 0, (size_t)out_size * sizeof(float), stream);
  if (ws_size < need) return;

  char* w = (char*)d_ws;
  unsigned* eg   = (unsigned*)w; w += SZ_E;
  float* h_ws = (float*)w; w += SZ_S;
  float* a_l  = (float*)w; w += SZ_S;
  float* b_l  = (float*)w; w += SZ_S;
  float* a_m  = (float*)w; w += SZ_S;
  float* b_m  = (float*)w; w += SZ_S;
  float* ms0  = (float*)w; w += SZ_S;
  float* ms1  = (float*)w; w += SZ_S;
  unsigned* wT   = (unsigned*)w; w += SZ_W;
  unsigned* wr1T = (unsigned*)w; w += SZ_W;
  unsigned* wr2T = (unsigned*)w; w += SZ_W2;
  float* embZ = (float*)w; w += SZ_TAB;
  float* embM = (float*)w; w += SZ_TAB;
  float* embU = (float*)w; w += SZ_TAB;

  hipLaunchKernelGGL(conv_w_kernel, dim3(256), dim3(256), 0, stream,
      Wl_e, Wm_e, Wu_e, Wu_m, Wr1, Wr2, emb, wT, wr1T, wr2T, embZ, embM, embU);

  hipLaunchKernelGGL(gru_proj_kernel, dim3(1024), dim3(256), 0, stream,
      0, ms0, ms1, node_features, h_ws, W_ih, W_hh, b_ih, b_hh,
      Wl_w, Wl_v, Wm_w, Wm_v, event_nums, a_l, b_l, a_m, b_m);

  for (int r = 0; r < 3; ++r) {
    if (r == 0) {
      hipLaunchKernelGGL(edge_round_first, dim3(8192), dim3(256), 0, stream,
          eg, wT, edge_ids, embZ, embM, embU,
          a_l, b_l, a_m, b_m, bl1, wl2, bl2, bm, bu, event_nums, ms0, ms1);
    } else {
      hipLaunchKernelGGL(edge_round_rest, dim3(8192), dim3(256), 0, stream,
          eg, wT, a_l, b_l, a_m, b_m, bl1, wl2, bl2, bm, bu, event_nums, ms0, ms1);
    }
    if (r < 2) {
      const float* hin = (r == 0) ? node_features : h_ws;
      hipLaunchKernelGGL(gru_proj_kernel, dim3(1024), dim3(256), 0, stream,
          1, ms0, ms1, hin, h_ws, W_ih, W_hh, b_ih, b_hh,
          Wl_w, Wl_v, Wm_w, Wm_v, event_nums, a_l, b_l, a_m, b_m);
    }
  }

  hipLaunchKernelGGL(readout_mfma, dim3(BB*127), dim3(256), 0, stream,
      eg, wr1T, wr2T, br1, br2, event_nums, (float*)d_out);
}